// Round 6
// baseline (6079.734 us; speedup 1.0000x reference)
//
#include <hip/hip_runtime.h>
#include <hip/hip_bf16.h>
#include <hip/hip_cooperative_groups.h>
#include <stdint.h>

namespace cg = cooperative_groups;

#define BATCH 32
#define CIN 128
#define HH 64
#define WW 64
#define MID 256
#define NCLS 65
#define HI 512
#define NWORDS 8      // 512 cols / 64 bits
#define HBS2 264      // hb row stride (halfs)
#define SEMS 68       // sem row stride (floats)
#define RMS 68        // rm row stride (floats)

typedef _Float16 half8 __attribute__((ext_vector_type(8)));
typedef _Float16 half4v __attribute__((ext_vector_type(4)));
typedef _Float16 half2v __attribute__((ext_vector_type(2)));
typedef float f32x4 __attribute__((ext_vector_type(4)));

// ---------------------------------------------------------------------------
// Pack w1 [m][c][ky][kx] into MFMA A-fragment layout, f16 hi/lo split.
// ---------------------------------------------------------------------------
__global__ __launch_bounds__(256) void prep_w1f(
    const float* __restrict__ w1, _Float16* __restrict__ w1fh,
    _Float16* __restrict__ w1fl)
{
    const int idx = blockIdx.x * 256 + threadIdx.x;   // < 294912
    const int j = idx & 7, lane = (idx >> 3) & 63, mt = (idx >> 9) & 15;
    const int s = (idx >> 13) & 3, kix = idx >> 15;
    const int m = mt * 16 + (lane & 15);
    const int c = s * 32 + (lane >> 4) * 8 + j;
    const int ky = kix / 3, kx = kix - ky * 3;
    const float v = w1[((m * CIN + c) * 3 + ky) * 3 + kx];
    const _Float16 hi = (_Float16)v;
    w1fh[idx] = hi;
    w1fl[idx] = (_Float16)(v - (float)hi);
}

// ---------------------------------------------------------------------------
// Pack w2 [o][m] into MFMA A-fragment layout (o padded 65->80), f16 hi/lo.
// ---------------------------------------------------------------------------
__global__ __launch_bounds__(256) void prep_w2f(
    const float* __restrict__ w2, _Float16* __restrict__ w2fh,
    _Float16* __restrict__ w2fl)
{
    const int idx = blockIdx.x * 256 + threadIdx.x;   // < 20480
    const int j = idx & 7, lane = (idx >> 3) & 63;
    const int ks = (idx >> 9) & 7, mt = idx >> 12;
    const int o = mt * 16 + (lane & 15);
    const int k = ks * 32 + (lane >> 4) * 8 + j;
    const float v = (o < NCLS) ? w2[o * MID + k] : 0.f;
    const _Float16 hi = (_Float16)v;
    w2fh[idx] = hi;
    w2fl[idx] = (_Float16)(v - (float)hi);
}

// ---------------------------------------------------------------------------
// MFMA head (unchanged): conv3x3 via 9 shifted GEMMs (f16 3-product split),
// bias+relu -> 1x1 MFMA -> softmax -> shuffle -> threshold.
// __launch_bounds__(256,3): total regs <=170 (unified VGPR+AGPR) -> 3 blk/CU.
// ---------------------------------------------------------------------------
__global__ __launch_bounds__(256, 3) void head_kernel(
    const float* __restrict__ x,
    const _Float16* __restrict__ w1fh, const _Float16* __restrict__ w1fl,
    const _Float16* __restrict__ w2fh, const _Float16* __restrict__ w2fl,
    const float* __restrict__ b1, const float* __restrict__ b2,
    float* __restrict__ out)
{
    const int b  = blockIdx.z;
    const int y0 = blockIdx.y * 8, x0 = blockIdx.x * 8;
    const int tid = threadIdx.x;
    const int lane = tid & 63, w = tid >> 6;
    const int n = lane & 15, q = lane >> 4;

    __shared__ __align__(16) unsigned char SM[51200];
    char* const xhb = (char*)SM;                   // hi plane, 100*256 B
    _Float16* const hbh = (_Float16*)SM;           // [32][HBS2] (overlays xps)
    _Float16* const hbl = hbh + 32 * HBS2;
    float* const sem  = (float*)(SM + 33792);      // [32][SEMS]
    float* const rinv = sem + 32 * SEMS;           // [32]

    const float* xb = x + (size_t)b * CIN * HH * WW;
    for (int i = tid; i < 6400; i += 256) {
        const int c2 = i / 100, pos = i - c2 * 100;
        const int r = pos / 10, cc = pos - r * 10;
        const int gy = y0 - 1 + r, gx = x0 - 1 + cc;
        float v0 = 0.f, v1 = 0.f;
        if ((unsigned)gy < HH && (unsigned)gx < WW) {
            const float* p = xb + (c2 * 2 * HH + gy) * WW + gx;
            v0 = p[0]; v1 = p[HH * WW];
        }
        const _Float16 h0 = (_Float16)v0, h1 = (_Float16)v1;
        half2v hi = {h0, h1};
        half2v lo = {(_Float16)(v0 - (float)h0), (_Float16)(v1 - (float)h1)};
        const int slot = (c2 >> 2) ^ (pos & 15);
        char* p16 = xhb + pos * 256 + (slot << 4) + (c2 & 3) * 4;
        *(half2v*)p16 = hi;
        *(half2v*)(p16 + 25600) = lo;
    }
    __syncthreads();

    f32x4 acc[4][4];
#pragma unroll
    for (int i = 0; i < 4; ++i)
#pragma unroll
        for (int t = 0; t < 4; ++t) acc[i][t] = (f32x4){0.f, 0.f, 0.f, 0.f};

    int bposT[4];
#pragma unroll
    for (int t = 0; t < 4; ++t)
        bposT[t] = (t * 2 + (n >> 3)) * 10 + (n & 7);

    for (int kix = 0; kix < 9; ++kix) {
        const int ky = kix / 3;
        const int koff = ky * 10 + (kix - ky * 3);
#pragma unroll
        for (int s = 0; s < 4; ++s) {
            half8 Bh[4], Bl[4];
#pragma unroll
            for (int t = 0; t < 4; ++t) {
                const int pos = bposT[t] + koff;
                const int byteoff = pos * 256 +
                    ((((s << 2) + q) ^ (pos & 15)) << 4);
                Bh[t] = *(const half8*)(xhb + byteoff);
                Bl[t] = *(const half8*)(xhb + 25600 + byteoff);
            }
#pragma unroll
            for (int i = 0; i < 4; ++i) {
                const size_t o = (size_t)(kix * 4 + s) * 8192 +
                                 (w * 4 + i) * 512 + lane * 8;
                const half8 Ah = *(const half8*)(w1fh + o);
                const half8 Al = *(const half8*)(w1fl + o);
#pragma unroll
                for (int t = 0; t < 4; ++t) {
                    acc[i][t] = __builtin_amdgcn_mfma_f32_16x16x32_f16(
                        Ah, Bh[t], acc[i][t], 0, 0, 0);
                    acc[i][t] = __builtin_amdgcn_mfma_f32_16x16x32_f16(
                        Ah, Bl[t], acc[i][t], 0, 0, 0);
                    acc[i][t] = __builtin_amdgcn_mfma_f32_16x16x32_f16(
                        Al, Bh[t], acc[i][t], 0, 0, 0);
                }
            }
        }
    }
    __syncthreads();

    for (int hf = 0; hf < 2; ++hf) {
        if (hf) __syncthreads();
#pragma unroll
        for (int i = 0; i < 4; ++i)
#pragma unroll
            for (int tt = 0; tt < 2; ++tt) {
                const int t = hf * 2 + tt;
                const int p = tt * 16 + n;
                const int m0 = w * 64 + i * 16 + q * 4;
                const f32x4 a = acc[i][t];
                const float4 bv = *(const float4*)(b1 + m0);
                const float h0 = fmaxf(a[0] + bv.x, 0.f);
                const float h1 = fmaxf(a[1] + bv.y, 0.f);
                const float h2 = fmaxf(a[2] + bv.z, 0.f);
                const float h3 = fmaxf(a[3] + bv.w, 0.f);
                half4v hh = {(_Float16)h0, (_Float16)h1,
                             (_Float16)h2, (_Float16)h3};
                half4v hl = {(_Float16)(h0 - (float)hh[0]),
                             (_Float16)(h1 - (float)hh[1]),
                             (_Float16)(h2 - (float)hh[2]),
                             (_Float16)(h3 - (float)hh[3])};
                *(half4v*)(hbh + p * HBS2 + m0) = hh;
                *(half4v*)(hbl + p * HBS2 + m0) = hl;
            }
        __syncthreads();
        {
            const int nt = w & 1;
            const int mt0 = (w < 2) ? 0 : 3;
            const int nmt = (w < 2) ? 3 : 2;
            const int pb = nt * 16 + n;
            f32x4 a2[3];
#pragma unroll
            for (int j = 0; j < 3; ++j) a2[j] = (f32x4){0.f, 0.f, 0.f, 0.f};
#pragma unroll
            for (int ks = 0; ks < 8; ++ks) {
                const int ad = pb * HBS2 + ks * 32 + q * 8;
                const half8 B2h = *(const half8*)(hbh + ad);
                const half8 B2l = *(const half8*)(hbl + ad);
#pragma unroll
                for (int j = 0; j < 3; ++j)
                    if (j < nmt) {
                        const size_t o = (size_t)((mt0 + j) * 8 + ks) * 512 +
                                         lane * 8;
                        const half8 A2h = *(const half8*)(w2fh + o);
                        const half8 A2l = *(const half8*)(w2fl + o);
                        a2[j] = __builtin_amdgcn_mfma_f32_16x16x32_f16(
                            A2h, B2h, a2[j], 0, 0, 0);
                        a2[j] = __builtin_amdgcn_mfma_f32_16x16x32_f16(
                            A2h, B2l, a2[j], 0, 0, 0);
                        a2[j] = __builtin_amdgcn_mfma_f32_16x16x32_f16(
                            A2l, B2h, a2[j], 0, 0, 0);
                    }
            }
#pragma unroll
            for (int j = 0; j < 3; ++j)
                if (j < nmt) {
                    const int o0 = (mt0 + j) * 16 + q * 4;
#pragma unroll
                    for (int r2 = 0; r2 < 4; ++r2) {
                        const int o = o0 + r2;
                        if (o < NCLS)
                            sem[pb * SEMS + o] = a2[j][r2] + b2[o];
                    }
                }
        }
        __syncthreads();
        if (tid < 128) {
            const int p = tid >> 2, q4 = tid & 3;
            const int o0 = q4 * 17;
            const int o1 = (o0 + 17 < NCLS) ? o0 + 17 : NCLS;
            float mx = -1e30f;
            for (int o = o0; o < o1; ++o)
                mx = fmaxf(mx, sem[p * SEMS + o]);
            mx = fmaxf(mx, __shfl_xor(mx, 1));
            mx = fmaxf(mx, __shfl_xor(mx, 2));
            float ssum = 0.f;
            for (int o = o0; o < o1; ++o) {
                float e = __expf(sem[p * SEMS + o] - mx);
                sem[p * SEMS + o] = e;
                ssum += e;
            }
            ssum += __shfl_xor(ssum, 1);
            ssum += __shfl_xor(ssum, 2);
            if (q4 == 0) rinv[p] = 1.f / ssum;
        }
        __syncthreads();
        for (int t2 = tid; t2 < 2048; t2 += 256) {
            const int p = t2 >> 6, o = t2 & 63;
            float v = sem[p * SEMS + o] * rinv[p];
            if (!(v >= 0.015f)) v = 0.f;
            const int P = hf * 32 + p;
            const int py = P >> 3, px = P & 7;
            const int row = (y0 + py) * 8 + (o >> 3);
            const int col = (x0 + px) * 8 + (o & 7);
            out[((size_t)b * HI + row) * HI + col] = v;
        }
    }
}

// ---------------------------------------------------------------------------
// NMS iteration body (shared by cooperative and fallback paths).
// Reads S direct from global (L2/L3-warm), suppression bits on the fly.
// ---------------------------------------------------------------------------
__device__ __forceinline__ void nms_body(
    const float* __restrict__ Sb, const uint64_t* __restrict__ Min,
    uint64_t* __restrict__ Mout, uint64_t* __restrict__ mk, bool last,
    int b, int bx, int ty, int tx, int tid,
    uint64_t* smw, uint64_t* hd, uint64_t* sup, float* rm)
{
    // P0: load mask halo
    if (tid < 240) {
        const int i = tid / 3, j = tid % 3;
        const int yy = ty - 8 + i;
        const int wj = bx - 1 + j;
        uint64_t v = 0;
        if (Min && (unsigned)yy < HI && (unsigned)wj < NWORDS)
            v = Min[((size_t)b * HI + yy) * NWORDS + wj];
        smw[tid] = v;
    }
    __syncthreads();
    // P1: horizontal dilate +-4
    if (tid < 240) {
        const int j = tid % 3;
        const uint64_t c = smw[tid];
        const uint64_t l = j > 0 ? smw[tid - 1] : 0ull;
        const uint64_t r = j < 2 ? smw[tid + 1] : 0ull;
        uint64_t d = c;
#pragma unroll
        for (int s = 1; s <= 4; ++s)
            d |= (c >> s) | (r << (64 - s)) | (c << s) | (l >> (64 - s));
        hd[tid] = d;
    }
    __syncthreads();
    // P2: vertical dilate +-4 -> sup
    if (tid < 216) {
        uint64_t v = 0;
#pragma unroll
        for (int k = 0; k < 9; ++k) v |= hd[tid + 3 * k];
        sup[tid] = v;
    }
    __syncthreads();

    for (int half = 0; half < 2; ++half) {
        const int rbase = half * 32;
        // hmax: 40 rows x 16 col-groups
        for (int k = tid; k < 640; k += 256) {
            const int rr = k >> 4, g = k & 15;
            const int r = rbase + rr;            // sup row (ty-4+r)
            const int gy = ty - 4 + r;
            const int x4 = g * 4;
            const int gx0 = tx + x4 - 4;
            float v[12];
            if ((unsigned)gy < HI) {
                const float* row = Sb + (size_t)gy * HI;
                if (gx0 >= 0 && gx0 <= HI - 12) {
                    const float4 A  = *(const float4*)(row + gx0);
                    const float4 Bq = *(const float4*)(row + gx0 + 4);
                    const float4 Cq = *(const float4*)(row + gx0 + 8);
                    v[0]=A.x; v[1]=A.y; v[2]=A.z; v[3]=A.w;
                    v[4]=Bq.x; v[5]=Bq.y; v[6]=Bq.z; v[7]=Bq.w;
                    v[8]=Cq.x; v[9]=Cq.y; v[10]=Cq.z; v[11]=Cq.w;
                } else {
#pragma unroll
                    for (int cc = 0; cc < 12; ++cc)
                        v[cc] = ((unsigned)(gx0 + cc) < HI) ? row[gx0 + cc]
                                                            : 0.f;
                }
            } else {
#pragma unroll
                for (int cc = 0; cc < 12; ++cc) v[cc] = 0.f;
            }
            const uint64_t* sr = sup + r * 3;
            const uint64_t w0 = sr[(60 + x4) >> 6];
            const uint64_t w1 = sr[(64 + x4) >> 6];
            const uint64_t w2 = sr[(68 + x4) >> 6];
            const int b0 = (60 + x4) & 63;
            const int b1 = (64 + x4) & 63;
            const int b2 = (68 + x4) & 63;
#pragma unroll
            for (int cc = 0; cc < 4; ++cc) {
                if ((w0 >> (b0 + cc)) & 1ull) v[cc] = 0.f;
                if ((w1 >> (b1 + cc)) & 1ull) v[4 + cc] = 0.f;
                if ((w2 >> (b2 + cc)) & 1ull) v[8 + cc] = 0.f;
            }
            const float m4567 = fmaxf(fmaxf(v[4],v[5]), fmaxf(v[6],v[7]));
            const float m23 = fmaxf(v[2],v[3]), m89 = fmaxf(v[8],v[9]);
            const float o0 = fmaxf(fmaxf(fmaxf(v[0],v[1]), m23),
                                   fmaxf(m4567, v[8]));
            const float o1 = fmaxf(fmaxf(v[1], m23), fmaxf(m4567, m89));
            const float o2 = fmaxf(fmaxf(m23, m4567), fmaxf(m89, v[10]));
            const float o3 = fmaxf(fmaxf(v[3], m4567),
                                   fmaxf(fmaxf(m89, v[10]), v[11]));
            *(float4*)(rm + rr * RMS + x4) = make_float4(o0,o1,o2,o3);
        }
        __syncthreads();
        // vmax + keep decision, 8 rows per wave
        {
            const int wv = tid >> 6, lane = tid & 63;
            const int rb = wv * 8;
            const int ybase = rbase + rb;
            float ring[9];
#pragma unroll
            for (int k = 0; k < 8; ++k) ring[k] = rm[(rb + k) * RMS + lane];
#pragma unroll
            for (int qq = 0; qq < 8; ++qq) {
                const int y = ybase + qq;
                ring[(qq + 8) % 9] = rm[(rb + qq + 8) * RMS + lane];
                float mv = ring[0];
#pragma unroll
                for (int k = 1; k < 9; ++k) mv = fmaxf(mv, ring[k]);
                float c = Sb[(size_t)(ty + y) * HI + tx + lane];
                if ((sup[(y + 4) * 3 + 1] >> lane) & 1ull) c = 0.f;
                const uint64_t oldw = smw[(y + 8) * 3 + 1];
                const bool keep = ((oldw >> lane) & 1ull) ||
                                  (c > 0.f && c == mv);
                const uint64_t word = __ballot(keep);
                if (lane == 0) {
                    if (last && mk)
                        mk[y] = word;
                    else
                        Mout[((size_t)b * HI + ty + y) * NWORDS + bx] = word;
                }
            }
        }
        __syncthreads();
    }
}

// ---------------------------------------------------------------------------
// Cooperative fused NMS: init + 8 updates + finalize in ONE launch.
// 2048 blocks, 8 blocks/CU (LDS 16960 B, __launch_bounds__(256,8)).
// grid.sync() + agent fences after EVERY update — including the last one:
// update 8 reads an S halo from neighbor tiles, and finalize writes S in
// place, so finalize must wait for the whole grid (round-5 bug).
// ---------------------------------------------------------------------------
__global__ __launch_bounds__(256, 8) void nms_all(
    float* __restrict__ S, uint64_t* __restrict__ MA,
    uint64_t* __restrict__ MB)
{
    cg::grid_group grid = cg::this_grid();

    const int b = blockIdx.z;
    const int bx = blockIdx.x;
    const int ty = blockIdx.y * 64, tx = bx * 64;
    const int tid = threadIdx.x;

    __shared__ uint64_t smw[80 * 3];
    __shared__ uint64_t hd[80 * 3];
    __shared__ uint64_t sup[72 * 3];
    __shared__ __align__(16) float rm[40 * RMS];
    __shared__ uint64_t mk[64];

    float* Sb = S + (size_t)b * HI * HI;

    for (int it = 0; it < 9; ++it) {
        const uint64_t* Min = (it == 0) ? (const uint64_t*)nullptr
                                        : ((it & 1) ? MA : MB);
        uint64_t* Mout = (it & 1) ? MB : MA;
        const bool last = (it == 8);

        nms_body(Sb, Min, Mout, mk, last, b, bx, ty, tx, tid,
                 smw, hd, sup, rm);

        __threadfence();
        grid.sync();
        __threadfence();
    }

    // ---- finalize: out = (mk bit && border) ? S : 0, own 64x64 tile ----
    for (int k = tid; k < 1024; k += 256) {
        const int r = k >> 4, c4 = k & 15;
        const int y = ty + r;
        const int xq = tx + c4 * 4;
        float4 v = *(const float4*)(Sb + (size_t)y * HI + xq);
        float* pv = (float*)&v;
        const uint64_t w = mk[r];
        const bool rowok = (y >= 4) && (y < HI - 4);
#pragma unroll
        for (int cc = 0; cc < 4; ++cc) {
            const int xx = xq + cc;
            const bool keep = rowok && (xx >= 4) && (xx < HI - 4) &&
                              ((w >> ((c4 * 4 + cc) & 63)) & 1ull);
            if (!keep) pv[cc] = 0.f;
        }
        *(float4*)(Sb + (size_t)y * HI + xq) = v;
    }
}

// ---------------------------------------------------------------------------
// Fallback: standalone lean NMS iteration (round-4 verified path).
// ---------------------------------------------------------------------------
__global__ __launch_bounds__(256, 8) void nms_iter(
    const float* __restrict__ S, const uint64_t* __restrict__ Min,
    uint64_t* __restrict__ Mout)
{
    const int b = blockIdx.z;
    const int bx = blockIdx.x;
    const int ty = blockIdx.y * 64, tx = bx * 64;
    const int tid = threadIdx.x;

    __shared__ uint64_t smw[80 * 3];
    __shared__ uint64_t hd[80 * 3];
    __shared__ uint64_t sup[72 * 3];
    __shared__ __align__(16) float rm[40 * RMS];

    nms_body(S + (size_t)b * HI * HI, Min, Mout, nullptr, false,
             b, bx, ty, tx, tid, smw, hd, sup, rm);
}

// ---------------------------------------------------------------------------
// Fallback finalize: out = (Mbit && border) ? S : 0, in place on d_out.
// ---------------------------------------------------------------------------
__global__ __launch_bounds__(256) void finalize_bits(
    float* __restrict__ S, const uint64_t* __restrict__ Mw)
{
    const int i4 = blockIdx.x * 256 + threadIdx.x;
    const size_t base = (size_t)i4 * 4;
    const int x = (int)(base & 511);
    const int y = (int)((base >> 9) & 511);
    const int bb = (int)(base >> 18);
    const uint64_t w = Mw[((size_t)bb * HI + y) * NWORDS + (x >> 6)];
    float4 v = ((const float4*)S)[i4];
    float* pv = (float*)&v;
    const bool rowok = (y >= 4) && (y < HI - 4);
#pragma unroll
    for (int cc = 0; cc < 4; ++cc) {
        const int xx = x + cc;
        const bool keep = rowok && (xx >= 4) && (xx < HI - 4) &&
                          ((w >> (xx & 63)) & 1ull);
        if (!keep) pv[cc] = 0.f;
    }
    ((float4*)S)[i4] = v;
}

extern "C" void kernel_launch(void* const* d_in, const int* in_sizes, int n_in,
                              void* d_out, int out_size, void* d_ws, size_t ws_size,
                              hipStream_t stream) {
    const float* x  = (const float*)d_in[0];
    const float* w1 = (const float*)d_in[1];
    const float* b1 = (const float*)d_in[2];
    const float* w2 = (const float*)d_in[3];
    const float* b2 = (const float*)d_in[4];
    float* out = (float*)d_out;

    char* wsb = (char*)d_ws;
    _Float16* w1fh = (_Float16*)(wsb);
    _Float16* w1fl = (_Float16*)(wsb + 0x90000);
    _Float16* w2fh = (_Float16*)(wsb + 0x120000);
    _Float16* w2fl = (_Float16*)(wsb + 0x130000);
    uint64_t* MA   = (uint64_t*)(wsb + 0x140000);
    uint64_t* MB   = (uint64_t*)(wsb + 0x240000);

    prep_w1f<<<294912 / 256, 256, 0, stream>>>(w1, w1fh, w1fl);
    prep_w2f<<<20480 / 256, 256, 0, stream>>>(w2, w2fh, w2fl);
    head_kernel<<<dim3(8, 8, BATCH), 256, 0, stream>>>(
        x, w1fh, w1fl, w2fh, w2fl, b1, b2, out);

    float* Sp = out;
    uint64_t* map = MA;
    uint64_t* mbp = MB;
    void* args[] = {&Sp, &map, &mbp};
    hipError_t cerr = hipLaunchCooperativeKernel(
        (const void*)nms_all, dim3(NWORDS, 8, BATCH), dim3(256, 1, 1),
        args, 0, stream);

    if (cerr != hipSuccess) {
        // Fallback: verified iterative path (round 4).
        dim3 g(NWORDS, 8, BATCH);
        nms_iter<<<g, 256, 0, stream>>>(out, nullptr, MA);
        for (int it = 0; it < 4; ++it) {
            nms_iter<<<g, 256, 0, stream>>>(out, MA, MB);
            nms_iter<<<g, 256, 0, stream>>>(out, MB, MA);
        }
        const int nf4 = BATCH * HI * HI / 4;
        finalize_bits<<<nf4 / 256, 256, 0, stream>>>(out, MA);
    }
}

// Round 7
// 598.771 us; speedup vs baseline: 10.1537x; 10.1537x over previous
//
#include <hip/hip_runtime.h>
#include <hip/hip_bf16.h>
#include <stdint.h>

#define BATCH 32
#define CIN 128
#define HH 64
#define WW 64
#define MID 256
#define NCLS 65
#define HI 512
#define NWORDS 8      // 512 cols / 64 bits
#define HBS2 264      // hb row stride (halfs)
#define SEMS 68       // sem row stride (floats)
#define RMS 68        // rm row stride (floats)

typedef _Float16 half8 __attribute__((ext_vector_type(8)));
typedef _Float16 half4v __attribute__((ext_vector_type(4)));
typedef _Float16 half2v __attribute__((ext_vector_type(2)));
typedef float f32x4 __attribute__((ext_vector_type(4)));

// ---------------------------------------------------------------------------
// Pack w1 [m][c][ky][kx] into MFMA A-fragment layout, f16 hi/lo split.
// ---------------------------------------------------------------------------
__global__ __launch_bounds__(256) void prep_w1f(
    const float* __restrict__ w1, _Float16* __restrict__ w1fh,
    _Float16* __restrict__ w1fl)
{
    const int idx = blockIdx.x * 256 + threadIdx.x;   // < 294912
    const int j = idx & 7, lane = (idx >> 3) & 63, mt = (idx >> 9) & 15;
    const int s = (idx >> 13) & 3, kix = idx >> 15;
    const int m = mt * 16 + (lane & 15);
    const int c = s * 32 + (lane >> 4) * 8 + j;
    const int ky = kix / 3, kx = kix - ky * 3;
    const float v = w1[((m * CIN + c) * 3 + ky) * 3 + kx];
    const _Float16 hi = (_Float16)v;
    w1fh[idx] = hi;
    w1fl[idx] = (_Float16)(v - (float)hi);
}

// ---------------------------------------------------------------------------
// Pack w2 [o][m] into MFMA A-fragment layout (o padded 65->80), f16 hi/lo.
// ---------------------------------------------------------------------------
__global__ __launch_bounds__(256) void prep_w2f(
    const float* __restrict__ w2, _Float16* __restrict__ w2fh,
    _Float16* __restrict__ w2fl)
{
    const int idx = blockIdx.x * 256 + threadIdx.x;   // < 20480
    const int j = idx & 7, lane = (idx >> 3) & 63;
    const int ks = (idx >> 9) & 7, mt = idx >> 12;
    const int o = mt * 16 + (lane & 15);
    const int k = ks * 32 + (lane >> 4) * 8 + j;
    const float v = (o < NCLS) ? w2[o * MID + k] : 0.f;
    const _Float16 hi = (_Float16)v;
    w2fh[idx] = hi;
    w2fl[idx] = (_Float16)(v - (float)hi);
}

// ---------------------------------------------------------------------------
// MFMA head (unchanged): conv3x3 via 9 shifted GEMMs (f16 3-product split),
// bias+relu -> 1x1 MFMA -> softmax -> shuffle -> threshold.
// ---------------------------------------------------------------------------
__global__ __launch_bounds__(256, 3) void head_kernel(
    const float* __restrict__ x,
    const _Float16* __restrict__ w1fh, const _Float16* __restrict__ w1fl,
    const _Float16* __restrict__ w2fh, const _Float16* __restrict__ w2fl,
    const float* __restrict__ b1, const float* __restrict__ b2,
    float* __restrict__ out)
{
    const int b  = blockIdx.z;
    const int y0 = blockIdx.y * 8, x0 = blockIdx.x * 8;
    const int tid = threadIdx.x;
    const int lane = tid & 63, w = tid >> 6;
    const int n = lane & 15, q = lane >> 4;

    __shared__ __align__(16) unsigned char SM[51200];
    char* const xhb = (char*)SM;                   // hi plane, 100*256 B
    _Float16* const hbh = (_Float16*)SM;           // [32][HBS2] (overlays xps)
    _Float16* const hbl = hbh + 32 * HBS2;
    float* const sem  = (float*)(SM + 33792);      // [32][SEMS]
    float* const rinv = sem + 32 * SEMS;           // [32]

    const float* xb = x + (size_t)b * CIN * HH * WW;
    for (int i = tid; i < 6400; i += 256) {
        const int c2 = i / 100, pos = i - c2 * 100;
        const int r = pos / 10, cc = pos - r * 10;
        const int gy = y0 - 1 + r, gx = x0 - 1 + cc;
        float v0 = 0.f, v1 = 0.f;
        if ((unsigned)gy < HH && (unsigned)gx < WW) {
            const float* p = xb + (c2 * 2 * HH + gy) * WW + gx;
            v0 = p[0]; v1 = p[HH * WW];
        }
        const _Float16 h0 = (_Float16)v0, h1 = (_Float16)v1;
        half2v hi = {h0, h1};
        half2v lo = {(_Float16)(v0 - (float)h0), (_Float16)(v1 - (float)h1)};
        const int slot = (c2 >> 2) ^ (pos & 15);
        char* p16 = xhb + pos * 256 + (slot << 4) + (c2 & 3) * 4;
        *(half2v*)p16 = hi;
        *(half2v*)(p16 + 25600) = lo;
    }
    __syncthreads();

    f32x4 acc[4][4];
#pragma unroll
    for (int i = 0; i < 4; ++i)
#pragma unroll
        for (int t = 0; t < 4; ++t) acc[i][t] = (f32x4){0.f, 0.f, 0.f, 0.f};

    int bposT[4];
#pragma unroll
    for (int t = 0; t < 4; ++t)
        bposT[t] = (t * 2 + (n >> 3)) * 10 + (n & 7);

    for (int kix = 0; kix < 9; ++kix) {
        const int ky = kix / 3;
        const int koff = ky * 10 + (kix - ky * 3);
#pragma unroll
        for (int s = 0; s < 4; ++s) {
            half8 Bh[4], Bl[4];
#pragma unroll
            for (int t = 0; t < 4; ++t) {
                const int pos = bposT[t] + koff;
                const int byteoff = pos * 256 +
                    ((((s << 2) + q) ^ (pos & 15)) << 4);
                Bh[t] = *(const half8*)(xhb + byteoff);
                Bl[t] = *(const half8*)(xhb + 25600 + byteoff);
            }
#pragma unroll
            for (int i = 0; i < 4; ++i) {
                const size_t o = (size_t)(kix * 4 + s) * 8192 +
                                 (w * 4 + i) * 512 + lane * 8;
                const half8 Ah = *(const half8*)(w1fh + o);
                const half8 Al = *(const half8*)(w1fl + o);
#pragma unroll
                for (int t = 0; t < 4; ++t) {
                    acc[i][t] = __builtin_amdgcn_mfma_f32_16x16x32_f16(
                        Ah, Bh[t], acc[i][t], 0, 0, 0);
                    acc[i][t] = __builtin_amdgcn_mfma_f32_16x16x32_f16(
                        Ah, Bl[t], acc[i][t], 0, 0, 0);
                    acc[i][t] = __builtin_amdgcn_mfma_f32_16x16x32_f16(
                        Al, Bh[t], acc[i][t], 0, 0, 0);
                }
            }
        }
    }
    __syncthreads();

    for (int hf = 0; hf < 2; ++hf) {
        if (hf) __syncthreads();
#pragma unroll
        for (int i = 0; i < 4; ++i)
#pragma unroll
            for (int tt = 0; tt < 2; ++tt) {
                const int t = hf * 2 + tt;
                const int p = tt * 16 + n;
                const int m0 = w * 64 + i * 16 + q * 4;
                const f32x4 a = acc[i][t];
                const float4 bv = *(const float4*)(b1 + m0);
                const float h0 = fmaxf(a[0] + bv.x, 0.f);
                const float h1 = fmaxf(a[1] + bv.y, 0.f);
                const float h2 = fmaxf(a[2] + bv.z, 0.f);
                const float h3 = fmaxf(a[3] + bv.w, 0.f);
                half4v hh = {(_Float16)h0, (_Float16)h1,
                             (_Float16)h2, (_Float16)h3};
                half4v hl = {(_Float16)(h0 - (float)hh[0]),
                             (_Float16)(h1 - (float)hh[1]),
                             (_Float16)(h2 - (float)hh[2]),
                             (_Float16)(h3 - (float)hh[3])};
                *(half4v*)(hbh + p * HBS2 + m0) = hh;
                *(half4v*)(hbl + p * HBS2 + m0) = hl;
            }
        __syncthreads();
        {
            const int nt = w & 1;
            const int mt0 = (w < 2) ? 0 : 3;
            const int nmt = (w < 2) ? 3 : 2;
            const int pb = nt * 16 + n;
            f32x4 a2[3];
#pragma unroll
            for (int j = 0; j < 3; ++j) a2[j] = (f32x4){0.f, 0.f, 0.f, 0.f};
#pragma unroll
            for (int ks = 0; ks < 8; ++ks) {
                const int ad = pb * HBS2 + ks * 32 + q * 8;
                const half8 B2h = *(const half8*)(hbh + ad);
                const half8 B2l = *(const half8*)(hbl + ad);
#pragma unroll
                for (int j = 0; j < 3; ++j)
                    if (j < nmt) {
                        const size_t o = (size_t)((mt0 + j) * 8 + ks) * 512 +
                                         lane * 8;
                        const half8 A2h = *(const half8*)(w2fh + o);
                        const half8 A2l = *(const half8*)(w2fl + o);
                        a2[j] = __builtin_amdgcn_mfma_f32_16x16x32_f16(
                            A2h, B2h, a2[j], 0, 0, 0);
                        a2[j] = __builtin_amdgcn_mfma_f32_16x16x32_f16(
                            A2h, B2l, a2[j], 0, 0, 0);
                        a2[j] = __builtin_amdgcn_mfma_f32_16x16x32_f16(
                            A2l, B2h, a2[j], 0, 0, 0);
                    }
            }
#pragma unroll
            for (int j = 0; j < 3; ++j)
                if (j < nmt) {
                    const int o0 = (mt0 + j) * 16 + q * 4;
#pragma unroll
                    for (int r2 = 0; r2 < 4; ++r2) {
                        const int o = o0 + r2;
                        if (o < NCLS)
                            sem[pb * SEMS + o] = a2[j][r2] + b2[o];
                    }
                }
        }
        __syncthreads();
        if (tid < 128) {
            const int p = tid >> 2, q4 = tid & 3;
            const int o0 = q4 * 17;
            const int o1 = (o0 + 17 < NCLS) ? o0 + 17 : NCLS;
            float mx = -1e30f;
            for (int o = o0; o < o1; ++o)
                mx = fmaxf(mx, sem[p * SEMS + o]);
            mx = fmaxf(mx, __shfl_xor(mx, 1));
            mx = fmaxf(mx, __shfl_xor(mx, 2));
            float ssum = 0.f;
            for (int o = o0; o < o1; ++o) {
                float e = __expf(sem[p * SEMS + o] - mx);
                sem[p * SEMS + o] = e;
                ssum += e;
            }
            ssum += __shfl_xor(ssum, 1);
            ssum += __shfl_xor(ssum, 2);
            if (q4 == 0) rinv[p] = 1.f / ssum;
        }
        __syncthreads();
        for (int t2 = tid; t2 < 2048; t2 += 256) {
            const int p = t2 >> 6, o = t2 & 63;
            float v = sem[p * SEMS + o] * rinv[p];
            if (!(v >= 0.015f)) v = 0.f;
            const int P = hf * 32 + p;
            const int py = P >> 3, px = P & 7;
            const int row = (y0 + py) * 8 + (o >> 3);
            const int col = (x0 + px) * 8 + (o & 7);
            out[((size_t)b * HI + row) * HI + col] = v;
        }
    }
}

// ---------------------------------------------------------------------------
// Lean fused PAIR of NMS updates (no S staging; S read direct from L2/L3).
// Pass A computes mask on the 80x80 halo region (rows/cols T-8..T+71) via
// 2 ballots -> 3 words per row; pass B computes the 64x64 tile using the
// in-LDS pass-A mask. With Min==null, pass A is the init max_mask.
// LDS = 36800 B -> 4 blocks/CU.
// ---------------------------------------------------------------------------
__global__ __launch_bounds__(256, 4) void nms_pair(
    const float* __restrict__ S, const uint64_t* __restrict__ Min,
    uint64_t* __restrict__ Mout)
{
    const int b = blockIdx.z;
    const int bx = blockIdx.x;
    const int ty = blockIdx.y * 64, tx = bx * 64;
    const int tid = threadIdx.x;

    __shared__ uint64_t smw[96 * 3];               // mask_in rows ty-16..+79
    __shared__ uint64_t hd[96 * 3];                // h-dilated (A: 96, B: 80)
    __shared__ uint64_t sup[88 * 3];               // supA (88) then supB (72)
    __shared__ uint64_t mkA[80 * 3];               // pass-A mask rows ty-8..+71
    __shared__ __align__(16) float hm[88 * 80];    // hmaxA; reused as rm (B)

    const float* Sb = S + (size_t)b * HI * HI;

    // P0: load mask_in rows ty-16..+79
    for (int k = tid; k < 288; k += 256) {
        const int i = k / 3, j = k - (k / 3) * 3;
        const int yy = ty - 16 + i;
        const int wj = bx - 1 + j;
        uint64_t v = 0;
        if (Min && (unsigned)yy < HI && (unsigned)wj < NWORDS)
            v = Min[((size_t)b * HI + yy) * NWORDS + wj];
        smw[k] = v;
    }
    __syncthreads();
    // P1: horizontal dilate +-4
    for (int k = tid; k < 288; k += 256) {
        const int j = k % 3;
        const uint64_t c = smw[k];
        const uint64_t l = j > 0 ? smw[k - 1] : 0ull;
        const uint64_t r = j < 2 ? smw[k + 1] : 0ull;
        uint64_t d = c;
#pragma unroll
        for (int s = 1; s <= 4; ++s)
            d |= (c >> s) | (r << (64 - s)) | (c << s) | (l >> (64 - s));
        hd[k] = d;
    }
    __syncthreads();
    // P2: vertical dilate -> supA rows ty-12..+75 (88)
    for (int k = tid; k < 264; k += 256) {
        uint64_t v = 0;
#pragma unroll
        for (int t = 0; t < 9; ++t) v |= hd[k + 3 * t];
        sup[k] = v;
    }
    __syncthreads();
    // P3: hmaxA — 88 rows x 20 col-groups (cols tx-8..+71)
    for (int k = tid; k < 1760; k += 256) {
        const int r = k / 20, g = k - (k / 20) * 20;
        const int gy = ty - 12 + r;
        const int gx0 = tx - 12 + 4 * g;
        float v[12];
        if ((unsigned)gy < HI) {
            const float* row = Sb + (size_t)gy * HI;
            if (gx0 >= 0 && gx0 <= HI - 12) {
                const float4 A  = *(const float4*)(row + gx0);
                const float4 Bq = *(const float4*)(row + gx0 + 4);
                const float4 Cq = *(const float4*)(row + gx0 + 8);
                v[0]=A.x; v[1]=A.y; v[2]=A.z; v[3]=A.w;
                v[4]=Bq.x; v[5]=Bq.y; v[6]=Bq.z; v[7]=Bq.w;
                v[8]=Cq.x; v[9]=Cq.y; v[10]=Cq.z; v[11]=Cq.w;
            } else {
#pragma unroll
                for (int cc = 0; cc < 12; ++cc)
                    v[cc] = ((unsigned)(gx0 + cc) < HI) ? row[gx0 + cc] : 0.f;
            }
        } else {
#pragma unroll
            for (int cc = 0; cc < 12; ++cc) v[cc] = 0.f;
        }
        const uint64_t* sr = sup + r * 3;
        const int rb0 = 52 + 4 * g;
        const uint64_t w0 = sr[rb0 >> 6];
        const uint64_t w1 = sr[(rb0 + 4) >> 6];
        const uint64_t w2 = sr[(rb0 + 8) >> 6];
        const int b0 = rb0 & 63, b1 = (rb0 + 4) & 63, b2 = (rb0 + 8) & 63;
#pragma unroll
        for (int cc = 0; cc < 4; ++cc) {
            if ((w0 >> (b0 + cc)) & 1ull) v[cc] = 0.f;
            if ((w1 >> (b1 + cc)) & 1ull) v[4 + cc] = 0.f;
            if ((w2 >> (b2 + cc)) & 1ull) v[8 + cc] = 0.f;
        }
        const float m4567 = fmaxf(fmaxf(v[4],v[5]), fmaxf(v[6],v[7]));
        const float m23 = fmaxf(v[2],v[3]), m89 = fmaxf(v[8],v[9]);
        const float o0 = fmaxf(fmaxf(fmaxf(v[0],v[1]), m23),
                               fmaxf(m4567, v[8]));
        const float o1 = fmaxf(fmaxf(v[1], m23), fmaxf(m4567, m89));
        const float o2 = fmaxf(fmaxf(m23, m4567), fmaxf(m89, v[10]));
        const float o3 = fmaxf(fmaxf(v[3], m4567),
                               fmaxf(fmaxf(m89, v[10]), v[11]));
        *(float4*)(hm + r * 80 + 4 * g) = make_float4(o0,o1,o2,o3);
    }
    __syncthreads();
    // P4: vmaxA + 2 ballots -> mkA (80 rows, cols tx-8..+71)
    {
        const int wv = tid >> 6, lane = tid & 63;
        const int a0 = wv * 20;
        float ringA[9], ringB[9];
#pragma unroll
        for (int t = 0; t < 8; ++t) {
            ringA[t] = hm[(a0 + t) * 80 + lane];
            ringB[t] = (lane < 16) ? hm[(a0 + t) * 80 + 64 + lane] : 0.f;
        }
        for (int ii = 0; ii < 20; ++ii) {
            const int a = a0 + ii;
            ringA[(ii + 8) % 9] = hm[(a + 8) * 80 + lane];
            ringB[(ii + 8) % 9] =
                (lane < 16) ? hm[(a + 8) * 80 + 64 + lane] : 0.f;
            float mvA = ringA[0], mvB = ringB[0];
#pragma unroll
            for (int t = 1; t < 9; ++t) {
                mvA = fmaxf(mvA, ringA[t]);
                mvB = fmaxf(mvB, ringB[t]);
            }
            const int gyA = ty - 8 + a;
            const int colA = tx - 8 + lane;
            float cA = 0.f;
            if ((unsigned)gyA < HI && (unsigned)colA < HI)
                cA = Sb[(size_t)gyA * HI + colA];
            if ((sup[(a + 4) * 3 + ((56 + lane) >> 6)] >>
                 ((56 + lane) & 63)) & 1ull)
                cA = 0.f;
            const bool bitA =
                (smw[(a + 8) * 3 + ((56 + lane) >> 6)] >>
                 ((56 + lane) & 63)) & 1ull;
            const bool keepA = bitA || (cA > 0.f && cA == mvA);
            bool keepB = false;
            if (lane < 16) {
                const int colB = tx + 56 + lane;
                float cB = 0.f;
                if ((unsigned)gyA < HI && (unsigned)colB < HI)
                    cB = Sb[(size_t)gyA * HI + colB];
                if ((sup[(a + 4) * 3 + ((120 + lane) >> 6)] >>
                     ((120 + lane) & 63)) & 1ull)
                    cB = 0.f;
                const bool bitB =
                    (smw[(a + 8) * 3 + ((120 + lane) >> 6)] >>
                     ((120 + lane) & 63)) & 1ull;
                keepB = bitB || (cB > 0.f && cB == mvB);
            }
            const uint64_t bA = __ballot(keepA);
            const uint64_t bB = __ballot(keepB);
            if (lane == 0) {
                mkA[a * 3 + 0] = (bA & 0xFFull) << 56;
                mkA[a * 3 + 1] = (bA >> 8) | ((bB & 0xFFull) << 56);
                mkA[a * 3 + 2] = (bB >> 8) & 0xFFull;
            }
        }
    }
    __syncthreads();
    // P5: horizontal dilate mkA (80 rows)
    for (int k = tid; k < 240; k += 256) {
        const int j = k % 3;
        const uint64_t c = mkA[k];
        const uint64_t l = j > 0 ? mkA[k - 1] : 0ull;
        const uint64_t r = j < 2 ? mkA[k + 1] : 0ull;
        uint64_t d = c;
#pragma unroll
        for (int s = 1; s <= 4; ++s)
            d |= (c >> s) | (r << (64 - s)) | (c << s) | (l >> (64 - s));
        hd[k] = d;
    }
    __syncthreads();
    // P6: vertical dilate -> supB rows ty-4..+67 (72)
    for (int k = tid; k < 216; k += 256) {
        uint64_t v = 0;
#pragma unroll
        for (int t = 0; t < 9; ++t) v |= hd[k + 3 * t];
        sup[k] = v;
    }
    __syncthreads();
    // P7: hmaxB — 72 rows x 16 col-groups into rm (reuse hm, stride 68)
    float* const rm = hm;
    for (int k = tid; k < 1152; k += 256) {
        const int r = k >> 4, g = k & 15;
        const int gy = ty - 4 + r;
        const int gx0 = tx + 4 * g - 4;
        float v[12];
        if ((unsigned)gy < HI) {
            const float* row = Sb + (size_t)gy * HI;
            if (gx0 >= 0 && gx0 <= HI - 12) {
                const float4 A  = *(const float4*)(row + gx0);
                const float4 Bq = *(const float4*)(row + gx0 + 4);
                const float4 Cq = *(const float4*)(row + gx0 + 8);
                v[0]=A.x; v[1]=A.y; v[2]=A.z; v[3]=A.w;
                v[4]=Bq.x; v[5]=Bq.y; v[6]=Bq.z; v[7]=Bq.w;
                v[8]=Cq.x; v[9]=Cq.y; v[10]=Cq.z; v[11]=Cq.w;
            } else {
#pragma unroll
                for (int cc = 0; cc < 12; ++cc)
                    v[cc] = ((unsigned)(gx0 + cc) < HI) ? row[gx0 + cc] : 0.f;
            }
        } else {
#pragma unroll
            for (int cc = 0; cc < 12; ++cc) v[cc] = 0.f;
        }
        const uint64_t* sr = sup + r * 3;
        const int rb0 = 60 + 4 * g;
        const uint64_t w0 = sr[rb0 >> 6];
        const uint64_t w1 = sr[(rb0 + 4) >> 6];
        const uint64_t w2 = sr[(rb0 + 8) >> 6];
        const int b0 = rb0 & 63, b1 = (rb0 + 4) & 63, b2 = (rb0 + 8) & 63;
#pragma unroll
        for (int cc = 0; cc < 4; ++cc) {
            if ((w0 >> (b0 + cc)) & 1ull) v[cc] = 0.f;
            if ((w1 >> (b1 + cc)) & 1ull) v[4 + cc] = 0.f;
            if ((w2 >> (b2 + cc)) & 1ull) v[8 + cc] = 0.f;
        }
        const float m4567 = fmaxf(fmaxf(v[4],v[5]), fmaxf(v[6],v[7]));
        const float m23 = fmaxf(v[2],v[3]), m89 = fmaxf(v[8],v[9]);
        const float o0 = fmaxf(fmaxf(fmaxf(v[0],v[1]), m23),
                               fmaxf(m4567, v[8]));
        const float o1 = fmaxf(fmaxf(v[1], m23), fmaxf(m4567, m89));
        const float o2 = fmaxf(fmaxf(m23, m4567), fmaxf(m89, v[10]));
        const float o3 = fmaxf(fmaxf(v[3], m4567),
                               fmaxf(fmaxf(m89, v[10]), v[11]));
        *(float4*)(rm + r * 68 + 4 * g) = make_float4(o0,o1,o2,o3);
    }
    __syncthreads();
    // P8: vmaxB + keep -> Mout (64 rows)
    {
        const int wv = tid >> 6, lane = tid & 63;
        const int y0w = wv * 16;
        float ring[9];
#pragma unroll
        for (int t = 0; t < 8; ++t) ring[t] = rm[(y0w + t) * 68 + lane];
        for (int ii = 0; ii < 16; ++ii) {
            const int y = y0w + ii;
            ring[(ii + 8) % 9] = rm[(y + 8) * 68 + lane];
            float mv = ring[0];
#pragma unroll
            for (int t = 1; t < 9; ++t) mv = fmaxf(mv, ring[t]);
            float c = Sb[(size_t)(ty + y) * HI + tx + lane];
            if ((sup[(y + 4) * 3 + 1] >> lane) & 1ull) c = 0.f;
            const bool old = (mkA[(y + 8) * 3 + 1] >> lane) & 1ull;
            const bool keep = old || (c > 0.f && c == mv);
            const uint64_t word = __ballot(keep);
            if (lane == 0)
                Mout[((size_t)b * HI + ty + y) * NWORDS + bx] = word;
        }
    }
}

// ---------------------------------------------------------------------------
// Last NMS update (u8) fused with finalize: reads S (workspace), computes the
// final keep decision and writes (keep && border) ? S : 0 straight to out.
// No in-place hazard because out != S. LDS 16.9 KB -> 8 blocks/CU.
// ---------------------------------------------------------------------------
__global__ __launch_bounds__(256, 8) void nms_last(
    const float* __restrict__ S, const uint64_t* __restrict__ Min,
    float* __restrict__ out)
{
    const int b = blockIdx.z;
    const int bx = blockIdx.x;
    const int ty = blockIdx.y * 64, tx = bx * 64;
    const int tid = threadIdx.x;

    __shared__ uint64_t smw[80 * 3];
    __shared__ uint64_t hd[80 * 3];
    __shared__ uint64_t sup[72 * 3];
    __shared__ __align__(16) float rm[40 * RMS];

    const float* Sb = S + (size_t)b * HI * HI;

    if (tid < 240) {
        const int i = tid / 3, j = tid % 3;
        const int yy = ty - 8 + i;
        const int wj = bx - 1 + j;
        uint64_t v = 0;
        if ((unsigned)yy < HI && (unsigned)wj < NWORDS)
            v = Min[((size_t)b * HI + yy) * NWORDS + wj];
        smw[tid] = v;
    }
    __syncthreads();
    if (tid < 240) {
        const int j = tid % 3;
        const uint64_t c = smw[tid];
        const uint64_t l = j > 0 ? smw[tid - 1] : 0ull;
        const uint64_t r = j < 2 ? smw[tid + 1] : 0ull;
        uint64_t d = c;
#pragma unroll
        for (int s = 1; s <= 4; ++s)
            d |= (c >> s) | (r << (64 - s)) | (c << s) | (l >> (64 - s));
        hd[tid] = d;
    }
    __syncthreads();
    if (tid < 216) {
        uint64_t v = 0;
#pragma unroll
        for (int k = 0; k < 9; ++k) v |= hd[tid + 3 * k];
        sup[tid] = v;
    }
    __syncthreads();

    for (int half = 0; half < 2; ++half) {
        const int rbase = half * 32;
        for (int k = tid; k < 640; k += 256) {
            const int rr = k >> 4, g = k & 15;
            const int r = rbase + rr;
            const int gy = ty - 4 + r;
            const int x4 = g * 4;
            const int gx0 = tx + x4 - 4;
            float v[12];
            if ((unsigned)gy < HI) {
                const float* row = Sb + (size_t)gy * HI;
                if (gx0 >= 0 && gx0 <= HI - 12) {
                    const float4 A  = *(const float4*)(row + gx0);
                    const float4 Bq = *(const float4*)(row + gx0 + 4);
                    const float4 Cq = *(const float4*)(row + gx0 + 8);
                    v[0]=A.x; v[1]=A.y; v[2]=A.z; v[3]=A.w;
                    v[4]=Bq.x; v[5]=Bq.y; v[6]=Bq.z; v[7]=Bq.w;
                    v[8]=Cq.x; v[9]=Cq.y; v[10]=Cq.z; v[11]=Cq.w;
                } else {
#pragma unroll
                    for (int cc = 0; cc < 12; ++cc)
                        v[cc] = ((unsigned)(gx0 + cc) < HI) ? row[gx0 + cc]
                                                            : 0.f;
                }
            } else {
#pragma unroll
                for (int cc = 0; cc < 12; ++cc) v[cc] = 0.f;
            }
            const uint64_t* sr = sup + r * 3;
            const uint64_t w0 = sr[(60 + x4) >> 6];
            const uint64_t w1 = sr[(64 + x4) >> 6];
            const uint64_t w2 = sr[(68 + x4) >> 6];
            const int b0 = (60 + x4) & 63;
            const int b1 = (64 + x4) & 63;
            const int b2 = (68 + x4) & 63;
#pragma unroll
            for (int cc = 0; cc < 4; ++cc) {
                if ((w0 >> (b0 + cc)) & 1ull) v[cc] = 0.f;
                if ((w1 >> (b1 + cc)) & 1ull) v[4 + cc] = 0.f;
                if ((w2 >> (b2 + cc)) & 1ull) v[8 + cc] = 0.f;
            }
            const float m4567 = fmaxf(fmaxf(v[4],v[5]), fmaxf(v[6],v[7]));
            const float m23 = fmaxf(v[2],v[3]), m89 = fmaxf(v[8],v[9]);
            const float o0 = fmaxf(fmaxf(fmaxf(v[0],v[1]), m23),
                                   fmaxf(m4567, v[8]));
            const float o1 = fmaxf(fmaxf(v[1], m23), fmaxf(m4567, m89));
            const float o2 = fmaxf(fmaxf(m23, m4567), fmaxf(m89, v[10]));
            const float o3 = fmaxf(fmaxf(v[3], m4567),
                                   fmaxf(fmaxf(m89, v[10]), v[11]));
            *(float4*)(rm + rr * RMS + x4) = make_float4(o0,o1,o2,o3);
        }
        __syncthreads();
        {
            const int wv = tid >> 6, lane = tid & 63;
            const int rb = wv * 8;
            const int ybase = rbase + rb;
            float ring[9];
#pragma unroll
            for (int k = 0; k < 8; ++k) ring[k] = rm[(rb + k) * RMS + lane];
#pragma unroll
            for (int qq = 0; qq < 8; ++qq) {
                const int y = ybase + qq;
                ring[(qq + 8) % 9] = rm[(rb + qq + 8) * RMS + lane];
                float mv = ring[0];
#pragma unroll
                for (int k = 1; k < 9; ++k) mv = fmaxf(mv, ring[k]);
                const int gy = ty + y, gx = tx + lane;
                const float corig = Sb[(size_t)gy * HI + gx];
                float c = corig;
                if ((sup[(y + 4) * 3 + 1] >> lane) & 1ull) c = 0.f;
                const uint64_t oldw = smw[(y + 8) * 3 + 1];
                const bool keep = ((oldw >> lane) & 1ull) ||
                                  (c > 0.f && c == mv);
                const bool border = (gy >= 4) && (gy < HI - 4) &&
                                    (gx >= 4) && (gx < HI - 4);
                out[((size_t)b * HI + gy) * HI + gx] =
                    (keep && border) ? corig : 0.f;
            }
        }
        __syncthreads();
    }
}

// ---------------------------------------------------------------------------
// Fallback single NMS iteration (round-4 verified) — used when ws too small.
// ---------------------------------------------------------------------------
__global__ __launch_bounds__(256, 8) void nms_iter(
    const float* __restrict__ S, const uint64_t* __restrict__ Min,
    uint64_t* __restrict__ Mout)
{
    const int b = blockIdx.z;
    const int bx = blockIdx.x;
    const int ty = blockIdx.y * 64, tx = bx * 64;
    const int tid = threadIdx.x;

    __shared__ uint64_t smw[80 * 3];
    __shared__ uint64_t hd[80 * 3];
    __shared__ uint64_t sup[72 * 3];
    __shared__ __align__(16) float rm[40 * RMS];

    const float* Sb = S + (size_t)b * HI * HI;

    if (tid < 240) {
        const int i = tid / 3, j = tid % 3;
        const int yy = ty - 8 + i;
        const int wj = bx - 1 + j;
        uint64_t v = 0;
        if (Min && (unsigned)yy < HI && (unsigned)wj < NWORDS)
            v = Min[((size_t)b * HI + yy) * NWORDS + wj];
        smw[tid] = v;
    }
    __syncthreads();
    if (tid < 240) {
        const int j = tid % 3;
        const uint64_t c = smw[tid];
        const uint64_t l = j > 0 ? smw[tid - 1] : 0ull;
        const uint64_t r = j < 2 ? smw[tid + 1] : 0ull;
        uint64_t d = c;
#pragma unroll
        for (int s = 1; s <= 4; ++s)
            d |= (c >> s) | (r << (64 - s)) | (c << s) | (l >> (64 - s));
        hd[tid] = d;
    }
    __syncthreads();
    if (tid < 216) {
        uint64_t v = 0;
#pragma unroll
        for (int k = 0; k < 9; ++k) v |= hd[tid + 3 * k];
        sup[tid] = v;
    }
    __syncthreads();

    for (int half = 0; half < 2; ++half) {
        const int rbase = half * 32;
        for (int k = tid; k < 640; k += 256) {
            const int rr = k >> 4, g = k & 15;
            const int r = rbase + rr;
            const int gy = ty - 4 + r;
            const int x4 = g * 4;
            const int gx0 = tx + x4 - 4;
            float v[12];
            if ((unsigned)gy < HI) {
                const float* row = Sb + (size_t)gy * HI;
                if (gx0 >= 0 && gx0 <= HI - 12) {
                    const float4 A  = *(const float4*)(row + gx0);
                    const float4 Bq = *(const float4*)(row + gx0 + 4);
                    const float4 Cq = *(const float4*)(row + gx0 + 8);
                    v[0]=A.x; v[1]=A.y; v[2]=A.z; v[3]=A.w;
                    v[4]=Bq.x; v[5]=Bq.y; v[6]=Bq.z; v[7]=Bq.w;
                    v[8]=Cq.x; v[9]=Cq.y; v[10]=Cq.z; v[11]=Cq.w;
                } else {
#pragma unroll
                    for (int cc = 0; cc < 12; ++cc)
                        v[cc] = ((unsigned)(gx0 + cc) < HI) ? row[gx0 + cc]
                                                            : 0.f;
                }
            } else {
#pragma unroll
                for (int cc = 0; cc < 12; ++cc) v[cc] = 0.f;
            }
            const uint64_t* sr = sup + r * 3;
            const uint64_t w0 = sr[(60 + x4) >> 6];
            const uint64_t w1 = sr[(64 + x4) >> 6];
            const uint64_t w2 = sr[(68 + x4) >> 6];
            const int b0 = (60 + x4) & 63;
            const int b1 = (64 + x4) & 63;
            const int b2 = (68 + x4) & 63;
#pragma unroll
            for (int cc = 0; cc < 4; ++cc) {
                if ((w0 >> (b0 + cc)) & 1ull) v[cc] = 0.f;
                if ((w1 >> (b1 + cc)) & 1ull) v[4 + cc] = 0.f;
                if ((w2 >> (b2 + cc)) & 1ull) v[8 + cc] = 0.f;
            }
            const float m4567 = fmaxf(fmaxf(v[4],v[5]), fmaxf(v[6],v[7]));
            const float m23 = fmaxf(v[2],v[3]), m89 = fmaxf(v[8],v[9]);
            const float o0 = fmaxf(fmaxf(fmaxf(v[0],v[1]), m23),
                                   fmaxf(m4567, v[8]));
            const float o1 = fmaxf(fmaxf(v[1], m23), fmaxf(m4567, m89));
            const float o2 = fmaxf(fmaxf(m23, m4567), fmaxf(m89, v[10]));
            const float o3 = fmaxf(fmaxf(v[3], m4567),
                                   fmaxf(fmaxf(m89, v[10]), v[11]));
            *(float4*)(rm + rr * RMS + x4) = make_float4(o0,o1,o2,o3);
        }
        __syncthreads();
        {
            const int wv = tid >> 6, lane = tid & 63;
            const int rb = wv * 8;
            const int ybase = rbase + rb;
            float ring[9];
#pragma unroll
            for (int k = 0; k < 8; ++k) ring[k] = rm[(rb + k) * RMS + lane];
#pragma unroll
            for (int qq = 0; qq < 8; ++qq) {
                const int y = ybase + qq;
                ring[(qq + 8) % 9] = rm[(rb + qq + 8) * RMS + lane];
                float mv = ring[0];
#pragma unroll
                for (int k = 1; k < 9; ++k) mv = fmaxf(mv, ring[k]);
                float c = Sb[(size_t)(ty + y) * HI + tx + lane];
                if ((sup[(y + 4) * 3 + 1] >> lane) & 1ull) c = 0.f;
                const uint64_t oldw = smw[(y + 8) * 3 + 1];
                const bool keep = ((oldw >> lane) & 1ull) ||
                                  (c > 0.f && c == mv);
                const uint64_t word = __ballot(keep);
                if (lane == 0)
                    Mout[((size_t)b * HI + ty + y) * NWORDS + bx] = word;
            }
        }
        __syncthreads();
    }
}

// ---------------------------------------------------------------------------
// Fallback finalize: out = (Mbit && border) ? S : 0, in place on d_out.
// ---------------------------------------------------------------------------
__global__ __launch_bounds__(256) void finalize_bits(
    float* __restrict__ S, const uint64_t* __restrict__ Mw)
{
    const int i4 = blockIdx.x * 256 + threadIdx.x;
    const size_t base = (size_t)i4 * 4;
    const int x = (int)(base & 511);
    const int y = (int)((base >> 9) & 511);
    const int bb = (int)(base >> 18);
    const uint64_t w = Mw[((size_t)bb * HI + y) * NWORDS + (x >> 6)];
    float4 v = ((const float4*)S)[i4];
    float* pv = (float*)&v;
    const bool rowok = (y >= 4) && (y < HI - 4);
#pragma unroll
    for (int cc = 0; cc < 4; ++cc) {
        const int xx = x + cc;
        const bool keep = rowok && (xx >= 4) && (xx < HI - 4) &&
                          ((w >> (xx & 63)) & 1ull);
        if (!keep) pv[cc] = 0.f;
    }
    ((float4*)S)[i4] = v;
}

extern "C" void kernel_launch(void* const* d_in, const int* in_sizes, int n_in,
                              void* d_out, int out_size, void* d_ws, size_t ws_size,
                              hipStream_t stream) {
    const float* x  = (const float*)d_in[0];
    const float* w1 = (const float*)d_in[1];
    const float* b1 = (const float*)d_in[2];
    const float* w2 = (const float*)d_in[3];
    const float* b2 = (const float*)d_in[4];
    float* out = (float*)d_out;

    char* wsb = (char*)d_ws;
    _Float16* w1fh = (_Float16*)(wsb);
    _Float16* w1fl = (_Float16*)(wsb + 0x90000);
    _Float16* w2fh = (_Float16*)(wsb + 0x120000);
    _Float16* w2fl = (_Float16*)(wsb + 0x130000);
    uint64_t* MA   = (uint64_t*)(wsb + 0x140000);
    uint64_t* MB   = (uint64_t*)(wsb + 0x240000);

    const size_t S_OFF = 0x340000;
    const size_t S_BYTES = (size_t)BATCH * HI * HI * 4;
    const bool use_ws = ws_size >= S_OFF + S_BYTES;
    float* S = use_ws ? (float*)(wsb + S_OFF) : out;

    prep_w1f<<<294912 / 256, 256, 0, stream>>>(w1, w1fh, w1fl);
    prep_w2f<<<20480 / 256, 256, 0, stream>>>(w2, w2fh, w2fl);
    head_kernel<<<dim3(8, 8, BATCH), 256, 0, stream>>>(
        x, w1fh, w1fl, w2fh, w2fl, b1, b2, S);

    dim3 g(NWORDS, 8, BATCH);
    // Updates: pair1 = init+u1 -> MA; pair2 = u2,u3 -> MB;
    //          pair3 = u4,u5 -> MA; pair4 = u6,u7 -> MB; last = u8.
    nms_pair<<<g, 256, 0, stream>>>(S, nullptr, MA);
    nms_pair<<<g, 256, 0, stream>>>(S, MA, MB);
    nms_pair<<<g, 256, 0, stream>>>(S, MB, MA);
    nms_pair<<<g, 256, 0, stream>>>(S, MA, MB);

    if (use_ws) {
        nms_last<<<g, 256, 0, stream>>>(S, MB, out);
    } else {
        nms_iter<<<g, 256, 0, stream>>>(S, MB, MA);
        const int nf4 = BATCH * HI * HI / 4;
        finalize_bits<<<nf4 / 256, 256, 0, stream>>>(out, MA);
    }
}

// Round 8
// 524.062 us; speedup vs baseline: 11.6012x; 1.1426x over previous
//
#include <hip/hip_runtime.h>
#include <hip/hip_bf16.h>
#include <stdint.h>

#define BATCH 32
#define CIN 128
#define HH 64
#define WW 64
#define MID 256
#define NCLS 65
#define HI 512
#define NWORDS 8      // 512 cols / 64 bits
#define HBS2 264      // hb row stride (halfs)
#define SEMS 68       // sem row stride (floats)
#define RMS 68        // rm row stride (floats)

typedef _Float16 half8 __attribute__((ext_vector_type(8)));
typedef _Float16 half4v __attribute__((ext_vector_type(4)));
typedef _Float16 half2v __attribute__((ext_vector_type(2)));
typedef float f32x4 __attribute__((ext_vector_type(4)));

// ---------------------------------------------------------------------------
// Merged weight prep: idx < 294912 -> w1 fragments; else w2 fragments.
// w1: (((kix*4+s)*16+mt)*64+lane)*8+j ; m=mt*16+(lane&15), c=s*32+(lane>>4)*8+j
// w2: ((mt*8+ks)*64+lane)*8+j ; o=mt*16+(lane&15) (o>=65 zero), k=ks*32+...
// ---------------------------------------------------------------------------
__global__ __launch_bounds__(256) void prep_wf(
    const float* __restrict__ w1, const float* __restrict__ w2,
    _Float16* __restrict__ w1fh, _Float16* __restrict__ w1fl,
    _Float16* __restrict__ w2fh, _Float16* __restrict__ w2fl)
{
    const int idx = blockIdx.x * 256 + threadIdx.x;   // < 315392
    if (idx < 294912) {
        const int j = idx & 7, lane = (idx >> 3) & 63, mt = (idx >> 9) & 15;
        const int s = (idx >> 13) & 3, kix = idx >> 15;
        const int m = mt * 16 + (lane & 15);
        const int c = s * 32 + (lane >> 4) * 8 + j;
        const int ky = kix / 3, kx = kix - ky * 3;
        const float v = w1[((m * CIN + c) * 3 + ky) * 3 + kx];
        const _Float16 hi = (_Float16)v;
        w1fh[idx] = hi;
        w1fl[idx] = (_Float16)(v - (float)hi);
    } else {
        const int i2 = idx - 294912;                  // < 20480
        const int j = i2 & 7, lane = (i2 >> 3) & 63;
        const int ks = (i2 >> 9) & 7, mt = i2 >> 12;
        const int o = mt * 16 + (lane & 15);
        const int k = ks * 32 + (lane >> 4) * 8 + j;
        const float v = (o < NCLS) ? w2[o * MID + k] : 0.f;
        const _Float16 hi = (_Float16)v;
        w2fh[i2] = hi;
        w2fl[i2] = (_Float16)(v - (float)hi);
    }
}

// ---------------------------------------------------------------------------
// MFMA head (unchanged, verified 247 us): conv3x3 via 9 shifted GEMMs
// (f16 3-product split), bias+relu -> 1x1 MFMA -> softmax -> threshold.
// __launch_bounds__(256,3): total regs <=170 (unified VGPR+AGPR) -> 3 blk/CU.
// ---------------------------------------------------------------------------
__global__ __launch_bounds__(256, 3) void head_kernel(
    const float* __restrict__ x,
    const _Float16* __restrict__ w1fh, const _Float16* __restrict__ w1fl,
    const _Float16* __restrict__ w2fh, const _Float16* __restrict__ w2fl,
    const float* __restrict__ b1, const float* __restrict__ b2,
    float* __restrict__ out)
{
    const int b  = blockIdx.z;
    const int y0 = blockIdx.y * 8, x0 = blockIdx.x * 8;
    const int tid = threadIdx.x;
    const int lane = tid & 63, w = tid >> 6;
    const int n = lane & 15, q = lane >> 4;

    __shared__ __align__(16) unsigned char SM[51200];
    char* const xhb = (char*)SM;                   // hi plane, 100*256 B
    _Float16* const hbh = (_Float16*)SM;           // [32][HBS2] (overlays xps)
    _Float16* const hbl = hbh + 32 * HBS2;
    float* const sem  = (float*)(SM + 33792);      // [32][SEMS]
    float* const rinv = sem + 32 * SEMS;           // [32]

    const float* xb = x + (size_t)b * CIN * HH * WW;
    for (int i = tid; i < 6400; i += 256) {
        const int c2 = i / 100, pos = i - c2 * 100;
        const int r = pos / 10, cc = pos - r * 10;
        const int gy = y0 - 1 + r, gx = x0 - 1 + cc;
        float v0 = 0.f, v1 = 0.f;
        if ((unsigned)gy < HH && (unsigned)gx < WW) {
            const float* p = xb + (c2 * 2 * HH + gy) * WW + gx;
            v0 = p[0]; v1 = p[HH * WW];
        }
        const _Float16 h0 = (_Float16)v0, h1 = (_Float16)v1;
        half2v hi = {h0, h1};
        half2v lo = {(_Float16)(v0 - (float)h0), (_Float16)(v1 - (float)h1)};
        const int slot = (c2 >> 2) ^ (pos & 15);
        char* p16 = xhb + pos * 256 + (slot << 4) + (c2 & 3) * 4;
        *(half2v*)p16 = hi;
        *(half2v*)(p16 + 25600) = lo;
    }
    __syncthreads();

    f32x4 acc[4][4];
#pragma unroll
    for (int i = 0; i < 4; ++i)
#pragma unroll
        for (int t = 0; t < 4; ++t) acc[i][t] = (f32x4){0.f, 0.f, 0.f, 0.f};

    int bposT[4];
#pragma unroll
    for (int t = 0; t < 4; ++t)
        bposT[t] = (t * 2 + (n >> 3)) * 10 + (n & 7);

    for (int kix = 0; kix < 9; ++kix) {
        const int ky = kix / 3;
        const int koff = ky * 10 + (kix - ky * 3);
#pragma unroll
        for (int s = 0; s < 4; ++s) {
            half8 Bh[4], Bl[4];
#pragma unroll
            for (int t = 0; t < 4; ++t) {
                const int pos = bposT[t] + koff;
                const int byteoff = pos * 256 +
                    ((((s << 2) + q) ^ (pos & 15)) << 4);
                Bh[t] = *(const half8*)(xhb + byteoff);
                Bl[t] = *(const half8*)(xhb + 25600 + byteoff);
            }
#pragma unroll
            for (int i = 0; i < 4; ++i) {
                const size_t o = (size_t)(kix * 4 + s) * 8192 +
                                 (w * 4 + i) * 512 + lane * 8;
                const half8 Ah = *(const half8*)(w1fh + o);
                const half8 Al = *(const half8*)(w1fl + o);
#pragma unroll
                for (int t = 0; t < 4; ++t) {
                    acc[i][t] = __builtin_amdgcn_mfma_f32_16x16x32_f16(
                        Ah, Bh[t], acc[i][t], 0, 0, 0);
                    acc[i][t] = __builtin_amdgcn_mfma_f32_16x16x32_f16(
                        Ah, Bl[t], acc[i][t], 0, 0, 0);
                    acc[i][t] = __builtin_amdgcn_mfma_f32_16x16x32_f16(
                        Al, Bh[t], acc[i][t], 0, 0, 0);
                }
            }
        }
    }
    __syncthreads();

    for (int hf = 0; hf < 2; ++hf) {
        if (hf) __syncthreads();
#pragma unroll
        for (int i = 0; i < 4; ++i)
#pragma unroll
            for (int tt = 0; tt < 2; ++tt) {
                const int t = hf * 2 + tt;
                const int p = tt * 16 + n;
                const int m0 = w * 64 + i * 16 + q * 4;
                const f32x4 a = acc[i][t];
                const float4 bv = *(const float4*)(b1 + m0);
                const float h0 = fmaxf(a[0] + bv.x, 0.f);
                const float h1 = fmaxf(a[1] + bv.y, 0.f);
                const float h2 = fmaxf(a[2] + bv.z, 0.f);
                const float h3 = fmaxf(a[3] + bv.w, 0.f);
                half4v hh = {(_Float16)h0, (_Float16)h1,
                             (_Float16)h2, (_Float16)h3};
                half4v hl = {(_Float16)(h0 - (float)hh[0]),
                             (_Float16)(h1 - (float)hh[1]),
                             (_Float16)(h2 - (float)hh[2]),
                             (_Float16)(h3 - (float)hh[3])};
                *(half4v*)(hbh + p * HBS2 + m0) = hh;
                *(half4v*)(hbl + p * HBS2 + m0) = hl;
            }
        __syncthreads();
        {
            const int nt = w & 1;
            const int mt0 = (w < 2) ? 0 : 3;
            const int nmt = (w < 2) ? 3 : 2;
            const int pb = nt * 16 + n;
            f32x4 a2[3];
#pragma unroll
            for (int j = 0; j < 3; ++j) a2[j] = (f32x4){0.f, 0.f, 0.f, 0.f};
#pragma unroll
            for (int ks = 0; ks < 8; ++ks) {
                const int ad = pb * HBS2 + ks * 32 + q * 8;
                const half8 B2h = *(const half8*)(hbh + ad);
                const half8 B2l = *(const half8*)(hbl + ad);
#pragma unroll
                for (int j = 0; j < 3; ++j)
                    if (j < nmt) {
                        const size_t o = (size_t)((mt0 + j) * 8 + ks) * 512 +
                                         lane * 8;
                        const half8 A2h = *(const half8*)(w2fh + o);
                        const half8 A2l = *(const half8*)(w2fl + o);
                        a2[j] = __builtin_amdgcn_mfma_f32_16x16x32_f16(
                            A2h, B2h, a2[j], 0, 0, 0);
                        a2[j] = __builtin_amdgcn_mfma_f32_16x16x32_f16(
                            A2h, B2l, a2[j], 0, 0, 0);
                        a2[j] = __builtin_amdgcn_mfma_f32_16x16x32_f16(
                            A2l, B2h, a2[j], 0, 0, 0);
                    }
            }
#pragma unroll
            for (int j = 0; j < 3; ++j)
                if (j < nmt) {
                    const int o0 = (mt0 + j) * 16 + q * 4;
#pragma unroll
                    for (int r2 = 0; r2 < 4; ++r2) {
                        const int o = o0 + r2;
                        if (o < NCLS)
                            sem[pb * SEMS + o] = a2[j][r2] + b2[o];
                    }
                }
        }
        __syncthreads();
        if (tid < 128) {
            const int p = tid >> 2, q4 = tid & 3;
            const int o0 = q4 * 17;
            const int o1 = (o0 + 17 < NCLS) ? o0 + 17 : NCLS;
            float mx = -1e30f;
            for (int o = o0; o < o1; ++o)
                mx = fmaxf(mx, sem[p * SEMS + o]);
            mx = fmaxf(mx, __shfl_xor(mx, 1));
            mx = fmaxf(mx, __shfl_xor(mx, 2));
            float ssum = 0.f;
            for (int o = o0; o < o1; ++o) {
                float e = __expf(sem[p * SEMS + o] - mx);
                sem[p * SEMS + o] = e;
                ssum += e;
            }
            ssum += __shfl_xor(ssum, 1);
            ssum += __shfl_xor(ssum, 2);
            if (q4 == 0) rinv[p] = 1.f / ssum;
        }
        __syncthreads();
        for (int t2 = tid; t2 < 2048; t2 += 256) {
            const int p = t2 >> 6, o = t2 & 63;
            float v = sem[p * SEMS + o] * rinv[p];
            if (!(v >= 0.015f)) v = 0.f;
            const int P = hf * 32 + p;
            const int py = P >> 3, px = P & 7;
            const int row = (y0 + py) * 8 + (o >> 3);
            const int col = (x0 + px) * 8 + (o & 7);
            out[((size_t)b * HI + row) * HI + col] = v;
        }
    }
}

// ---------------------------------------------------------------------------
// Lean NMS iteration (round-4 verified): no S staging, direct L2/L3 reads,
// suppression bits applied on the fly. LDS 16.9 KB -> 8 blocks/CU.
// Init specialization: Min==null skips the mask load/dilate phases
// (uniform branch), just zeroes smw/sup.
// ---------------------------------------------------------------------------
__global__ __launch_bounds__(256, 8) void nms_iter(
    const float* __restrict__ S, const uint64_t* __restrict__ Min,
    uint64_t* __restrict__ Mout)
{
    const int b = blockIdx.z;
    const int bx = blockIdx.x;
    const int ty = blockIdx.y * 64, tx = bx * 64;
    const int tid = threadIdx.x;

    __shared__ uint64_t smw[80 * 3];
    __shared__ uint64_t hd[80 * 3];
    __shared__ uint64_t sup[72 * 3];
    __shared__ __align__(16) float rm[40 * RMS];

    const float* Sb = S + (size_t)b * HI * HI;

    if (Min) {
        if (tid < 240) {
            const int i = tid / 3, j = tid % 3;
            const int yy = ty - 8 + i;
            const int wj = bx - 1 + j;
            uint64_t v = 0;
            if ((unsigned)yy < HI && (unsigned)wj < NWORDS)
                v = Min[((size_t)b * HI + yy) * NWORDS + wj];
            smw[tid] = v;
        }
        __syncthreads();
        if (tid < 240) {
            const int j = tid % 3;
            const uint64_t c = smw[tid];
            const uint64_t l = j > 0 ? smw[tid - 1] : 0ull;
            const uint64_t r = j < 2 ? smw[tid + 1] : 0ull;
            uint64_t d = c;
#pragma unroll
            for (int s = 1; s <= 4; ++s)
                d |= (c >> s) | (r << (64 - s)) | (c << s) | (l >> (64 - s));
            hd[tid] = d;
        }
        __syncthreads();
        if (tid < 216) {
            uint64_t v = 0;
#pragma unroll
            for (int k = 0; k < 9; ++k) v |= hd[tid + 3 * k];
            sup[tid] = v;
        }
        __syncthreads();
    } else {
        if (tid < 240) smw[tid] = 0;
        if (tid < 216) sup[tid] = 0;
        __syncthreads();
    }

    for (int half = 0; half < 2; ++half) {
        const int rbase = half * 32;
        for (int k = tid; k < 640; k += 256) {
            const int rr = k >> 4, g = k & 15;
            const int r = rbase + rr;
            const int gy = ty - 4 + r;
            const int x4 = g * 4;
            const int gx0 = tx + x4 - 4;
            float v[12];
            if ((unsigned)gy < HI) {
                const float* row = Sb + (size_t)gy * HI;
                if (gx0 >= 0 && gx0 <= HI - 12) {
                    const float4 A  = *(const float4*)(row + gx0);
                    const float4 Bq = *(const float4*)(row + gx0 + 4);
                    const float4 Cq = *(const float4*)(row + gx0 + 8);
                    v[0]=A.x; v[1]=A.y; v[2]=A.z; v[3]=A.w;
                    v[4]=Bq.x; v[5]=Bq.y; v[6]=Bq.z; v[7]=Bq.w;
                    v[8]=Cq.x; v[9]=Cq.y; v[10]=Cq.z; v[11]=Cq.w;
                } else {
#pragma unroll
                    for (int cc = 0; cc < 12; ++cc)
                        v[cc] = ((unsigned)(gx0 + cc) < HI) ? row[gx0 + cc]
                                                            : 0.f;
                }
            } else {
#pragma unroll
                for (int cc = 0; cc < 12; ++cc) v[cc] = 0.f;
            }
            const uint64_t* sr = sup + r * 3;
            const uint64_t w0 = sr[(60 + x4) >> 6];
            const uint64_t w1 = sr[(64 + x4) >> 6];
            const uint64_t w2 = sr[(68 + x4) >> 6];
            const int b0 = (60 + x4) & 63;
            const int b1 = (64 + x4) & 63;
            const int b2 = (68 + x4) & 63;
#pragma unroll
            for (int cc = 0; cc < 4; ++cc) {
                if ((w0 >> (b0 + cc)) & 1ull) v[cc] = 0.f;
                if ((w1 >> (b1 + cc)) & 1ull) v[4 + cc] = 0.f;
                if ((w2 >> (b2 + cc)) & 1ull) v[8 + cc] = 0.f;
            }
            const float m4567 = fmaxf(fmaxf(v[4],v[5]), fmaxf(v[6],v[7]));
            const float m23 = fmaxf(v[2],v[3]), m89 = fmaxf(v[8],v[9]);
            const float o0 = fmaxf(fmaxf(fmaxf(v[0],v[1]), m23),
                                   fmaxf(m4567, v[8]));
            const float o1 = fmaxf(fmaxf(v[1], m23), fmaxf(m4567, m89));
            const float o2 = fmaxf(fmaxf(m23, m4567), fmaxf(m89, v[10]));
            const float o3 = fmaxf(fmaxf(v[3], m4567),
                                   fmaxf(fmaxf(m89, v[10]), v[11]));
            *(float4*)(rm + rr * RMS + x4) = make_float4(o0,o1,o2,o3);
        }
        __syncthreads();
        {
            const int wv = tid >> 6, lane = tid & 63;
            const int rb = wv * 8;
            const int ybase = rbase + rb;
            float ring[9];
#pragma unroll
            for (int k = 0; k < 8; ++k) ring[k] = rm[(rb + k) * RMS + lane];
#pragma unroll
            for (int qq = 0; qq < 8; ++qq) {
                const int y = ybase + qq;
                ring[(qq + 8) % 9] = rm[(rb + qq + 8) * RMS + lane];
                float mv = ring[0];
#pragma unroll
                for (int k = 1; k < 9; ++k) mv = fmaxf(mv, ring[k]);
                float c = Sb[(size_t)(ty + y) * HI + tx + lane];
                if ((sup[(y + 4) * 3 + 1] >> lane) & 1ull) c = 0.f;
                const uint64_t oldw = smw[(y + 8) * 3 + 1];
                const bool keep = ((oldw >> lane) & 1ull) ||
                                  (c > 0.f && c == mv);
                const uint64_t word = __ballot(keep);
                if (lane == 0)
                    Mout[((size_t)b * HI + ty + y) * NWORDS + bx] = word;
            }
        }
        __syncthreads();
    }
}

// ---------------------------------------------------------------------------
// Last NMS update (u8) fused with finalize (verified in round 7): reads S
// (workspace), computes final keep and writes (keep && border) ? S : 0
// straight to out. No in-place hazard because out != S.
// ---------------------------------------------------------------------------
__global__ __launch_bounds__(256, 8) void nms_last(
    const float* __restrict__ S, const uint64_t* __restrict__ Min,
    float* __restrict__ out)
{
    const int b = blockIdx.z;
    const int bx = blockIdx.x;
    const int ty = blockIdx.y * 64, tx = bx * 64;
    const int tid = threadIdx.x;

    __shared__ uint64_t smw[80 * 3];
    __shared__ uint64_t hd[80 * 3];
    __shared__ uint64_t sup[72 * 3];
    __shared__ __align__(16) float rm[40 * RMS];

    const float* Sb = S + (size_t)b * HI * HI;

    if (tid < 240) {
        const int i = tid / 3, j = tid % 3;
        const int yy = ty - 8 + i;
        const int wj = bx - 1 + j;
        uint64_t v = 0;
        if ((unsigned)yy < HI && (unsigned)wj < NWORDS)
            v = Min[((size_t)b * HI + yy) * NWORDS + wj];
        smw[tid] = v;
    }
    __syncthreads();
    if (tid < 240) {
        const int j = tid % 3;
        const uint64_t c = smw[tid];
        const uint64_t l = j > 0 ? smw[tid - 1] : 0ull;
        const uint64_t r = j < 2 ? smw[tid + 1] : 0ull;
        uint64_t d = c;
#pragma unroll
        for (int s = 1; s <= 4; ++s)
            d |= (c >> s) | (r << (64 - s)) | (c << s) | (l >> (64 - s));
        hd[tid] = d;
    }
    __syncthreads();
    if (tid < 216) {
        uint64_t v = 0;
#pragma unroll
        for (int k = 0; k < 9; ++k) v |= hd[tid + 3 * k];
        sup[tid] = v;
    }
    __syncthreads();

    for (int half = 0; half < 2; ++half) {
        const int rbase = half * 32;
        for (int k = tid; k < 640; k += 256) {
            const int rr = k >> 4, g = k & 15;
            const int r = rbase + rr;
            const int gy = ty - 4 + r;
            const int x4 = g * 4;
            const int gx0 = tx + x4 - 4;
            float v[12];
            if ((unsigned)gy < HI) {
                const float* row = Sb + (size_t)gy * HI;
                if (gx0 >= 0 && gx0 <= HI - 12) {
                    const float4 A  = *(const float4*)(row + gx0);
                    const float4 Bq = *(const float4*)(row + gx0 + 4);
                    const float4 Cq = *(const float4*)(row + gx0 + 8);
                    v[0]=A.x; v[1]=A.y; v[2]=A.z; v[3]=A.w;
                    v[4]=Bq.x; v[5]=Bq.y; v[6]=Bq.z; v[7]=Bq.w;
                    v[8]=Cq.x; v[9]=Cq.y; v[10]=Cq.z; v[11]=Cq.w;
                } else {
#pragma unroll
                    for (int cc = 0; cc < 12; ++cc)
                        v[cc] = ((unsigned)(gx0 + cc) < HI) ? row[gx0 + cc]
                                                            : 0.f;
                }
            } else {
#pragma unroll
                for (int cc = 0; cc < 12; ++cc) v[cc] = 0.f;
            }
            const uint64_t* sr = sup + r * 3;
            const uint64_t w0 = sr[(60 + x4) >> 6];
            const uint64_t w1 = sr[(64 + x4) >> 6];
            const uint64_t w2 = sr[(68 + x4) >> 6];
            const int b0 = (60 + x4) & 63;
            const int b1 = (64 + x4) & 63;
            const int b2 = (68 + x4) & 63;
#pragma unroll
            for (int cc = 0; cc < 4; ++cc) {
                if ((w0 >> (b0 + cc)) & 1ull) v[cc] = 0.f;
                if ((w1 >> (b1 + cc)) & 1ull) v[4 + cc] = 0.f;
                if ((w2 >> (b2 + cc)) & 1ull) v[8 + cc] = 0.f;
            }
            const float m4567 = fmaxf(fmaxf(v[4],v[5]), fmaxf(v[6],v[7]));
            const float m23 = fmaxf(v[2],v[3]), m89 = fmaxf(v[8],v[9]);
            const float o0 = fmaxf(fmaxf(fmaxf(v[0],v[1]), m23),
                                   fmaxf(m4567, v[8]));
            const float o1 = fmaxf(fmaxf(v[1], m23), fmaxf(m4567, m89));
            const float o2 = fmaxf(fmaxf(m23, m4567), fmaxf(m89, v[10]));
            const float o3 = fmaxf(fmaxf(v[3], m4567),
                                   fmaxf(fmaxf(m89, v[10]), v[11]));
            *(float4*)(rm + rr * RMS + x4) = make_float4(o0,o1,o2,o3);
        }
        __syncthreads();
        {
            const int wv = tid >> 6, lane = tid & 63;
            const int rb = wv * 8;
            const int ybase = rbase + rb;
            float ring[9];
#pragma unroll
            for (int k = 0; k < 8; ++k) ring[k] = rm[(rb + k) * RMS + lane];
#pragma unroll
            for (int qq = 0; qq < 8; ++qq) {
                const int y = ybase + qq;
                ring[(qq + 8) % 9] = rm[(rb + qq + 8) * RMS + lane];
                float mv = ring[0];
#pragma unroll
                for (int k = 1; k < 9; ++k) mv = fmaxf(mv, ring[k]);
                const int gy = ty + y, gx = tx + lane;
                const float corig = Sb[(size_t)gy * HI + gx];
                float c = corig;
                if ((sup[(y + 4) * 3 + 1] >> lane) & 1ull) c = 0.f;
                const uint64_t oldw = smw[(y + 8) * 3 + 1];
                const bool keep = ((oldw >> lane) & 1ull) ||
                                  (c > 0.f && c == mv);
                const bool border = (gy >= 4) && (gy < HI - 4) &&
                                    (gx >= 4) && (gx < HI - 4);
                out[((size_t)b * HI + gy) * HI + gx] =
                    (keep && border) ? corig : 0.f;
            }
        }
        __syncthreads();
    }
}

// ---------------------------------------------------------------------------
// Fallback finalize (only used when ws too small for S).
// ---------------------------------------------------------------------------
__global__ __launch_bounds__(256) void finalize_bits(
    float* __restrict__ S, const uint64_t* __restrict__ Mw)
{
    const int i4 = blockIdx.x * 256 + threadIdx.x;
    const size_t base = (size_t)i4 * 4;
    const int x = (int)(base & 511);
    const int y = (int)((base >> 9) & 511);
    const int bb = (int)(base >> 18);
    const uint64_t w = Mw[((size_t)bb * HI + y) * NWORDS + (x >> 6)];
    float4 v = ((const float4*)S)[i4];
    float* pv = (float*)&v;
    const bool rowok = (y >= 4) && (y < HI - 4);
#pragma unroll
    for (int cc = 0; cc < 4; ++cc) {
        const int xx = x + cc;
        const bool keep = rowok && (xx >= 4) && (xx < HI - 4) &&
                          ((w >> (xx & 63)) & 1ull);
        if (!keep) pv[cc] = 0.f;
    }
    ((float4*)S)[i4] = v;
}

extern "C" void kernel_launch(void* const* d_in, const int* in_sizes, int n_in,
                              void* d_out, int out_size, void* d_ws, size_t ws_size,
                              hipStream_t stream) {
    const float* x  = (const float*)d_in[0];
    const float* w1 = (const float*)d_in[1];
    const float* b1 = (const float*)d_in[2];
    const float* w2 = (const float*)d_in[3];
    const float* b2 = (const float*)d_in[4];
    float* out = (float*)d_out;

    char* wsb = (char*)d_ws;
    _Float16* w1fh = (_Float16*)(wsb);
    _Float16* w1fl = (_Float16*)(wsb + 0x90000);
    _Float16* w2fh = (_Float16*)(wsb + 0x120000);
    _Float16* w2fl = (_Float16*)(wsb + 0x130000);
    uint64_t* MA   = (uint64_t*)(wsb + 0x140000);
    uint64_t* MB   = (uint64_t*)(wsb + 0x240000);

    const size_t S_OFF = 0x340000;
    const size_t S_BYTES = (size_t)BATCH * HI * HI * 4;
    const bool use_ws = ws_size >= S_OFF + S_BYTES;
    float* S = use_ws ? (float*)(wsb + S_OFF) : out;

    prep_wf<<<1232, 256, 0, stream>>>(w1, w2, w1fh, w1fl, w2fh, w2fl);
    head_kernel<<<dim3(8, 8, BATCH), 256, 0, stream>>>(
        x, w1fh, w1fl, w2fh, w2fl, b1, b2, S);

    dim3 g(NWORDS, 8, BATCH);
    // init + updates 1..7 via nms_iter (8 launches), update 8 fused with
    // finalize in nms_last.
    nms_iter<<<g, 256, 0, stream>>>(S, nullptr, MA);   // init
    nms_iter<<<g, 256, 0, stream>>>(S, MA, MB);        // u1
    nms_iter<<<g, 256, 0, stream>>>(S, MB, MA);        // u2
    nms_iter<<<g, 256, 0, stream>>>(S, MA, MB);        // u3
    nms_iter<<<g, 256, 0, stream>>>(S, MB, MA);        // u4
    nms_iter<<<g, 256, 0, stream>>>(S, MA, MB);        // u5
    nms_iter<<<g, 256, 0, stream>>>(S, MB, MA);        // u6
    nms_iter<<<g, 256, 0, stream>>>(S, MA, MB);        // u7

    if (use_ws) {
        nms_last<<<g, 256, 0, stream>>>(S, MB, out);   // u8 + finalize
    } else {
        nms_iter<<<g, 256, 0, stream>>>(S, MB, MA);    // u8
        const int nf4 = BATCH * HI * HI / 4;
        finalize_bits<<<nf4 / 256, 256, 0, stream>>>(out, MA);
    }
}

// Round 9
// 521.693 us; speedup vs baseline: 11.6539x; 1.0045x over previous
//
#include <hip/hip_runtime.h>
#include <hip/hip_bf16.h>
#include <stdint.h>

#define BATCH 32
#define CIN 128
#define HH 64
#define WW 64
#define MID 256
#define NCLS 65
#define HI 512
#define NWORDS 8      // 512 cols / 64 bits
#define HBS2 264      // hb row stride (halfs)
#define SEMS 68       // sem row stride (floats)
#define RMS 68        // rm row stride (floats)

typedef _Float16 half8 __attribute__((ext_vector_type(8)));
typedef _Float16 half4v __attribute__((ext_vector_type(4)));
typedef _Float16 half2v __attribute__((ext_vector_type(2)));
typedef float f32x4 __attribute__((ext_vector_type(4)));

// ---------------------------------------------------------------------------
// Merged weight prep: idx < 294912 -> w1 fragments; else w2 fragments.
// ---------------------------------------------------------------------------
__global__ __launch_bounds__(256) void prep_wf(
    const float* __restrict__ w1, const float* __restrict__ w2,
    _Float16* __restrict__ w1fh, _Float16* __restrict__ w1fl,
    _Float16* __restrict__ w2fh, _Float16* __restrict__ w2fl)
{
    const int idx = blockIdx.x * 256 + threadIdx.x;   // < 315392
    if (idx < 294912) {
        const int j = idx & 7, lane = (idx >> 3) & 63, mt = (idx >> 9) & 15;
        const int s = (idx >> 13) & 3, kix = idx >> 15;
        const int m = mt * 16 + (lane & 15);
        const int c = s * 32 + (lane >> 4) * 8 + j;
        const int ky = kix / 3, kx = kix - ky * 3;
        const float v = w1[((m * CIN + c) * 3 + ky) * 3 + kx];
        const _Float16 hi = (_Float16)v;
        w1fh[idx] = hi;
        w1fl[idx] = (_Float16)(v - (float)hi);
    } else {
        const int i2 = idx - 294912;                  // < 20480
        const int j = i2 & 7, lane = (i2 >> 3) & 63;
        const int ks = (i2 >> 9) & 7, mt = i2 >> 12;
        const int o = mt * 16 + (lane & 15);
        const int k = ks * 32 + (lane >> 4) * 8 + j;
        const float v = (o < NCLS) ? w2[o * MID + k] : 0.f;
        const _Float16 hi = (_Float16)v;
        w2fh[i2] = hi;
        w2fl[i2] = (_Float16)(v - (float)hi);
    }
}

// ---------------------------------------------------------------------------
// MFMA head (unchanged, verified ~250 us): conv3x3 via 9 shifted GEMMs
// (f16 3-product split), bias+relu -> 1x1 MFMA -> softmax -> threshold.
// __launch_bounds__(256,3): total regs <=170 (unified VGPR+AGPR) -> 3 blk/CU.
// ---------------------------------------------------------------------------
__global__ __launch_bounds__(256, 3) void head_kernel(
    const float* __restrict__ x,
    const _Float16* __restrict__ w1fh, const _Float16* __restrict__ w1fl,
    const _Float16* __restrict__ w2fh, const _Float16* __restrict__ w2fl,
    const float* __restrict__ b1, const float* __restrict__ b2,
    float* __restrict__ out)
{
    const int b  = blockIdx.z;
    const int y0 = blockIdx.y * 8, x0 = blockIdx.x * 8;
    const int tid = threadIdx.x;
    const int lane = tid & 63, w = tid >> 6;
    const int n = lane & 15, q = lane >> 4;

    __shared__ __align__(16) unsigned char SM[51200];
    char* const xhb = (char*)SM;                   // hi plane, 100*256 B
    _Float16* const hbh = (_Float16*)SM;           // [32][HBS2] (overlays xps)
    _Float16* const hbl = hbh + 32 * HBS2;
    float* const sem  = (float*)(SM + 33792);      // [32][SEMS]
    float* const rinv = sem + 32 * SEMS;           // [32]

    const float* xb = x + (size_t)b * CIN * HH * WW;
    for (int i = tid; i < 6400; i += 256) {
        const int c2 = i / 100, pos = i - c2 * 100;
        const int r = pos / 10, cc = pos - r * 10;
        const int gy = y0 - 1 + r, gx = x0 - 1 + cc;
        float v0 = 0.f, v1 = 0.f;
        if ((unsigned)gy < HH && (unsigned)gx < WW) {
            const float* p = xb + (c2 * 2 * HH + gy) * WW + gx;
            v0 = p[0]; v1 = p[HH * WW];
        }
        const _Float16 h0 = (_Float16)v0, h1 = (_Float16)v1;
        half2v hi = {h0, h1};
        half2v lo = {(_Float16)(v0 - (float)h0), (_Float16)(v1 - (float)h1)};
        const int slot = (c2 >> 2) ^ (pos & 15);
        char* p16 = xhb + pos * 256 + (slot << 4) + (c2 & 3) * 4;
        *(half2v*)p16 = hi;
        *(half2v*)(p16 + 25600) = lo;
    }
    __syncthreads();

    f32x4 acc[4][4];
#pragma unroll
    for (int i = 0; i < 4; ++i)
#pragma unroll
        for (int t = 0; t < 4; ++t) acc[i][t] = (f32x4){0.f, 0.f, 0.f, 0.f};

    int bposT[4];
#pragma unroll
    for (int t = 0; t < 4; ++t)
        bposT[t] = (t * 2 + (n >> 3)) * 10 + (n & 7);

    for (int kix = 0; kix < 9; ++kix) {
        const int ky = kix / 3;
        const int koff = ky * 10 + (kix - ky * 3);
#pragma unroll
        for (int s = 0; s < 4; ++s) {
            half8 Bh[4], Bl[4];
#pragma unroll
            for (int t = 0; t < 4; ++t) {
                const int pos = bposT[t] + koff;
                const int byteoff = pos * 256 +
                    ((((s << 2) + q) ^ (pos & 15)) << 4);
                Bh[t] = *(const half8*)(xhb + byteoff);
                Bl[t] = *(const half8*)(xhb + 25600 + byteoff);
            }
#pragma unroll
            for (int i = 0; i < 4; ++i) {
                const size_t o = (size_t)(kix * 4 + s) * 8192 +
                                 (w * 4 + i) * 512 + lane * 8;
                const half8 Ah = *(const half8*)(w1fh + o);
                const half8 Al = *(const half8*)(w1fl + o);
#pragma unroll
                for (int t = 0; t < 4; ++t) {
                    acc[i][t] = __builtin_amdgcn_mfma_f32_16x16x32_f16(
                        Ah, Bh[t], acc[i][t], 0, 0, 0);
                    acc[i][t] = __builtin_amdgcn_mfma_f32_16x16x32_f16(
                        Ah, Bl[t], acc[i][t], 0, 0, 0);
                    acc[i][t] = __builtin_amdgcn_mfma_f32_16x16x32_f16(
                        Al, Bh[t], acc[i][t], 0, 0, 0);
                }
            }
        }
    }
    __syncthreads();

    for (int hf = 0; hf < 2; ++hf) {
        if (hf) __syncthreads();
#pragma unroll
        for (int i = 0; i < 4; ++i)
#pragma unroll
            for (int tt = 0; tt < 2; ++tt) {
                const int t = hf * 2 + tt;
                const int p = tt * 16 + n;
                const int m0 = w * 64 + i * 16 + q * 4;
                const f32x4 a = acc[i][t];
                const float4 bv = *(const float4*)(b1 + m0);
                const float h0 = fmaxf(a[0] + bv.x, 0.f);
                const float h1 = fmaxf(a[1] + bv.y, 0.f);
                const float h2 = fmaxf(a[2] + bv.z, 0.f);
                const float h3 = fmaxf(a[3] + bv.w, 0.f);
                half4v hh = {(_Float16)h0, (_Float16)h1,
                             (_Float16)h2, (_Float16)h3};
                half4v hl = {(_Float16)(h0 - (float)hh[0]),
                             (_Float16)(h1 - (float)hh[1]),
                             (_Float16)(h2 - (float)hh[2]),
                             (_Float16)(h3 - (float)hh[3])};
                *(half4v*)(hbh + p * HBS2 + m0) = hh;
                *(half4v*)(hbl + p * HBS2 + m0) = hl;
            }
        __syncthreads();
        {
            const int nt = w & 1;
            const int mt0 = (w < 2) ? 0 : 3;
            const int nmt = (w < 2) ? 3 : 2;
            const int pb = nt * 16 + n;
            f32x4 a2[3];
#pragma unroll
            for (int j = 0; j < 3; ++j) a2[j] = (f32x4){0.f, 0.f, 0.f, 0.f};
#pragma unroll
            for (int ks = 0; ks < 8; ++ks) {
                const int ad = pb * HBS2 + ks * 32 + q * 8;
                const half8 B2h = *(const half8*)(hbh + ad);
                const half8 B2l = *(const half8*)(hbl + ad);
#pragma unroll
                for (int j = 0; j < 3; ++j)
                    if (j < nmt) {
                        const size_t o = (size_t)((mt0 + j) * 8 + ks) * 512 +
                                         lane * 8;
                        const half8 A2h = *(const half8*)(w2fh + o);
                        const half8 A2l = *(const half8*)(w2fl + o);
                        a2[j] = __builtin_amdgcn_mfma_f32_16x16x32_f16(
                            A2h, B2h, a2[j], 0, 0, 0);
                        a2[j] = __builtin_amdgcn_mfma_f32_16x16x32_f16(
                            A2h, B2l, a2[j], 0, 0, 0);
                        a2[j] = __builtin_amdgcn_mfma_f32_16x16x32_f16(
                            A2l, B2h, a2[j], 0, 0, 0);
                    }
            }
#pragma unroll
            for (int j = 0; j < 3; ++j)
                if (j < nmt) {
                    const int o0 = (mt0 + j) * 16 + q * 4;
#pragma unroll
                    for (int r2 = 0; r2 < 4; ++r2) {
                        const int o = o0 + r2;
                        if (o < NCLS)
                            sem[pb * SEMS + o] = a2[j][r2] + b2[o];
                    }
                }
        }
        __syncthreads();
        if (tid < 128) {
            const int p = tid >> 2, q4 = tid & 3;
            const int o0 = q4 * 17;
            const int o1 = (o0 + 17 < NCLS) ? o0 + 17 : NCLS;
            float mx = -1e30f;
            for (int o = o0; o < o1; ++o)
                mx = fmaxf(mx, sem[p * SEMS + o]);
            mx = fmaxf(mx, __shfl_xor(mx, 1));
            mx = fmaxf(mx, __shfl_xor(mx, 2));
            float ssum = 0.f;
            for (int o = o0; o < o1; ++o) {
                float e = __expf(sem[p * SEMS + o] - mx);
                sem[p * SEMS + o] = e;
                ssum += e;
            }
            ssum += __shfl_xor(ssum, 1);
            ssum += __shfl_xor(ssum, 2);
            if (q4 == 0) rinv[p] = 1.f / ssum;
        }
        __syncthreads();
        for (int t2 = tid; t2 < 2048; t2 += 256) {
            const int p = t2 >> 6, o = t2 & 63;
            float v = sem[p * SEMS + o] * rinv[p];
            if (!(v >= 0.015f)) v = 0.f;
            const int P = hf * 32 + p;
            const int py = P >> 3, px = P & 7;
            const int row = (y0 + py) * 8 + (o >> 3);
            const int col = (x0 + px) * 8 + (o & 7);
            out[((size_t)b * HI + row) * HI + col] = v;
        }
    }
}

// ---------------------------------------------------------------------------
// hmax phase helper: each lane loads only its OWN aligned float4 (always
// in-bounds), applies suppression (always sup word 1, bit x4+cc), gets
// neighbors via __shfl(lane +-1). Edge groups (g=0/15) load a 4-float halo
// that overrides the wrap-around shfl. Read volume = exactly the window.
// ---------------------------------------------------------------------------
__device__ __forceinline__ void nms_hmax_phase(
    const float* __restrict__ Sb, const uint64_t* __restrict__ sup,
    float* __restrict__ rm, int ty, int tx, int tid, int rbase)
{
    const int lane = tid & 63;
    for (int k = tid; k < 640; k += 256) {
        const int rr = k >> 4, g = k & 15;
        const int r = rbase + rr;
        const int gy = ty - 4 + r;
        const int x4 = g * 4;
        const uint64_t* sr = sup + r * 3;
        float own[4] = {0.f, 0.f, 0.f, 0.f};
        float halo[4] = {0.f, 0.f, 0.f, 0.f};
        if ((unsigned)gy < HI) {
            const float* row = Sb + (size_t)gy * HI;
            const float4 o4 = *(const float4*)(row + tx + x4);
            own[0] = o4.x; own[1] = o4.y; own[2] = o4.z; own[3] = o4.w;
            const uint64_t w1 = sr[1];
#pragma unroll
            for (int cc = 0; cc < 4; ++cc)
                if ((w1 >> (x4 + cc)) & 1ull) own[cc] = 0.f;
            if (g == 0 && tx >= 4) {
                const float4 h4 = *(const float4*)(row + tx - 4);
                halo[0] = h4.x; halo[1] = h4.y; halo[2] = h4.z; halo[3] = h4.w;
                const uint64_t w0 = sr[0];
#pragma unroll
                for (int cc = 0; cc < 4; ++cc)
                    if ((w0 >> (60 + cc)) & 1ull) halo[cc] = 0.f;
            } else if (g == 15 && tx + 64 < HI) {
                const float4 h4 = *(const float4*)(row + tx + 64);
                halo[0] = h4.x; halo[1] = h4.y; halo[2] = h4.z; halo[3] = h4.w;
                const uint64_t w2 = sr[2];
#pragma unroll
                for (int cc = 0; cc < 4; ++cc)
                    if ((w2 >> cc) & 1ull) halo[cc] = 0.f;
            }
        }
        // all lanes in the active iteration execute the shuffles
        float v[12];
#pragma unroll
        for (int cc = 0; cc < 4; ++cc) {
            v[4 + cc] = own[cc];
            v[cc]     = __shfl(own[cc], lane - 1);
            v[8 + cc] = __shfl(own[cc], lane + 1);
        }
        if (g == 0) {
#pragma unroll
            for (int cc = 0; cc < 4; ++cc) v[cc] = halo[cc];
        } else if (g == 15) {
#pragma unroll
            for (int cc = 0; cc < 4; ++cc) v[8 + cc] = halo[cc];
        }
        const float m4567 = fmaxf(fmaxf(v[4],v[5]), fmaxf(v[6],v[7]));
        const float m23 = fmaxf(v[2],v[3]), m89 = fmaxf(v[8],v[9]);
        const float o0 = fmaxf(fmaxf(fmaxf(v[0],v[1]), m23),
                               fmaxf(m4567, v[8]));
        const float o1 = fmaxf(fmaxf(v[1], m23), fmaxf(m4567, m89));
        const float o2 = fmaxf(fmaxf(m23, m4567), fmaxf(m89, v[10]));
        const float o3 = fmaxf(fmaxf(v[3], m4567),
                               fmaxf(fmaxf(m89, v[10]), v[11]));
        *(float4*)(rm + rr * RMS + x4) = make_float4(o0,o1,o2,o3);
    }
}

// ---------------------------------------------------------------------------
// Lean NMS iteration: no S staging, shfl-shared hmax reads, suppression on
// the fly. LDS 16.9 KB -> 8 blocks/CU. Min==null -> init (skip mask phases).
// ---------------------------------------------------------------------------
__global__ __launch_bounds__(256, 8) void nms_iter(
    const float* __restrict__ S, const uint64_t* __restrict__ Min,
    uint64_t* __restrict__ Mout)
{
    const int b = blockIdx.z;
    const int bx = blockIdx.x;
    const int ty = blockIdx.y * 64, tx = bx * 64;
    const int tid = threadIdx.x;

    __shared__ uint64_t smw[80 * 3];
    __shared__ uint64_t hd[80 * 3];
    __shared__ uint64_t sup[72 * 3];
    __shared__ __align__(16) float rm[40 * RMS];

    const float* Sb = S + (size_t)b * HI * HI;

    if (Min) {
        if (tid < 240) {
            const int i = tid / 3, j = tid % 3;
            const int yy = ty - 8 + i;
            const int wj = bx - 1 + j;
            uint64_t v = 0;
            if ((unsigned)yy < HI && (unsigned)wj < NWORDS)
                v = Min[((size_t)b * HI + yy) * NWORDS + wj];
            smw[tid] = v;
        }
        __syncthreads();
        if (tid < 240) {
            const int j = tid % 3;
            const uint64_t c = smw[tid];
            const uint64_t l = j > 0 ? smw[tid - 1] : 0ull;
            const uint64_t r = j < 2 ? smw[tid + 1] : 0ull;
            uint64_t d = c;
#pragma unroll
            for (int s = 1; s <= 4; ++s)
                d |= (c >> s) | (r << (64 - s)) | (c << s) | (l >> (64 - s));
            hd[tid] = d;
        }
        __syncthreads();
        if (tid < 216) {
            uint64_t v = 0;
#pragma unroll
            for (int k = 0; k < 9; ++k) v |= hd[tid + 3 * k];
            sup[tid] = v;
        }
        __syncthreads();
    } else {
        if (tid < 240) smw[tid] = 0;
        if (tid < 216) sup[tid] = 0;
        __syncthreads();
    }

    for (int half = 0; half < 2; ++half) {
        const int rbase = half * 32;
        nms_hmax_phase(Sb, sup, rm, ty, tx, tid, rbase);
        __syncthreads();
        {
            const int wv = tid >> 6, lane = tid & 63;
            const int rb = wv * 8;
            const int ybase = rbase + rb;
            float ring[9];
#pragma unroll
            for (int k = 0; k < 8; ++k) ring[k] = rm[(rb + k) * RMS + lane];
#pragma unroll
            for (int qq = 0; qq < 8; ++qq) {
                const int y = ybase + qq;
                ring[(qq + 8) % 9] = rm[(rb + qq + 8) * RMS + lane];
                float mv = ring[0];
#pragma unroll
                for (int k = 1; k < 9; ++k) mv = fmaxf(mv, ring[k]);
                float c = Sb[(size_t)(ty + y) * HI + tx + lane];
                if ((sup[(y + 4) * 3 + 1] >> lane) & 1ull) c = 0.f;
                const uint64_t oldw = smw[(y + 8) * 3 + 1];
                const bool keep = ((oldw >> lane) & 1ull) ||
                                  (c > 0.f && c == mv);
                const uint64_t word = __ballot(keep);
                if (lane == 0)
                    Mout[((size_t)b * HI + ty + y) * NWORDS + bx] = word;
            }
        }
        __syncthreads();
    }
}

// ---------------------------------------------------------------------------
// Last NMS update (u8) fused with finalize: reads S (workspace), writes
// (keep && border) ? S : 0 straight to out. No in-place hazard (out != S).
// ---------------------------------------------------------------------------
__global__ __launch_bounds__(256, 8) void nms_last(
    const float* __restrict__ S, const uint64_t* __restrict__ Min,
    float* __restrict__ out)
{
    const int b = blockIdx.z;
    const int bx = blockIdx.x;
    const int ty = blockIdx.y * 64, tx = bx * 64;
    const int tid = threadIdx.x;

    __shared__ uint64_t smw[80 * 3];
    __shared__ uint64_t hd[80 * 3];
    __shared__ uint64_t sup[72 * 3];
    __shared__ __align__(16) float rm[40 * RMS];

    const float* Sb = S + (size_t)b * HI * HI;

    if (tid < 240) {
        const int i = tid / 3, j = tid % 3;
        const int yy = ty - 8 + i;
        const int wj = bx - 1 + j;
        uint64_t v = 0;
        if ((unsigned)yy < HI && (unsigned)wj < NWORDS)
            v = Min[((size_t)b * HI + yy) * NWORDS + wj];
        smw[tid] = v;
    }
    __syncthreads();
    if (tid < 240) {
        const int j = tid % 3;
        const uint64_t c = smw[tid];
        const uint64_t l = j > 0 ? smw[tid - 1] : 0ull;
        const uint64_t r = j < 2 ? smw[tid + 1] : 0ull;
        uint64_t d = c;
#pragma unroll
        for (int s = 1; s <= 4; ++s)
            d |= (c >> s) | (r << (64 - s)) | (c << s) | (l >> (64 - s));
        hd[tid] = d;
    }
    __syncthreads();
    if (tid < 216) {
        uint64_t v = 0;
#pragma unroll
        for (int k = 0; k < 9; ++k) v |= hd[tid + 3 * k];
        sup[tid] = v;
    }
    __syncthreads();

    for (int half = 0; half < 2; ++half) {
        const int rbase = half * 32;
        nms_hmax_phase(Sb, sup, rm, ty, tx, tid, rbase);
        __syncthreads();
        {
            const int wv = tid >> 6, lane = tid & 63;
            const int rb = wv * 8;
            const int ybase = rbase + rb;
            float ring[9];
#pragma unroll
            for (int k = 0; k < 8; ++k) ring[k] = rm[(rb + k) * RMS + lane];
#pragma unroll
            for (int qq = 0; qq < 8; ++qq) {
                const int y = ybase + qq;
                ring[(qq + 8) % 9] = rm[(rb + qq + 8) * RMS + lane];
                float mv = ring[0];
#pragma unroll
                for (int k = 1; k < 9; ++k) mv = fmaxf(mv, ring[k]);
                const int gy = ty + y, gx = tx + lane;
                const float corig = Sb[(size_t)gy * HI + gx];
                float c = corig;
                if ((sup[(y + 4) * 3 + 1] >> lane) & 1ull) c = 0.f;
                const uint64_t oldw = smw[(y + 8) * 3 + 1];
                const bool keep = ((oldw >> lane) & 1ull) ||
                                  (c > 0.f && c == mv);
                const bool border = (gy >= 4) && (gy < HI - 4) &&
                                    (gx >= 4) && (gx < HI - 4);
                out[((size_t)b * HI + gy) * HI + gx] =
                    (keep && border) ? corig : 0.f;
            }
        }
        __syncthreads();
    }
}

// ---------------------------------------------------------------------------
// Fallback finalize (only used when ws too small for S).
// ---------------------------------------------------------------------------
__global__ __launch_bounds__(256) void finalize_bits(
    float* __restrict__ S, const uint64_t* __restrict__ Mw)
{
    const int i4 = blockIdx.x * 256 + threadIdx.x;
    const size_t base = (size_t)i4 * 4;
    const int x = (int)(base & 511);
    const int y = (int)((base >> 9) & 511);
    const int bb = (int)(base >> 18);
    const uint64_t w = Mw[((size_t)bb * HI + y) * NWORDS + (x >> 6)];
    float4 v = ((const float4*)S)[i4];
    float* pv = (float*)&v;
    const bool rowok = (y >= 4) && (y < HI - 4);
#pragma unroll
    for (int cc = 0; cc < 4; ++cc) {
        const int xx = x + cc;
        const bool keep = rowok && (xx >= 4) && (xx < HI - 4) &&
                          ((w >> (xx & 63)) & 1ull);
        if (!keep) pv[cc] = 0.f;
    }
    ((float4*)S)[i4] = v;
}

extern "C" void kernel_launch(void* const* d_in, const int* in_sizes, int n_in,
                              void* d_out, int out_size, void* d_ws, size_t ws_size,
                              hipStream_t stream) {
    const float* x  = (const float*)d_in[0];
    const float* w1 = (const float*)d_in[1];
    const float* b1 = (const float*)d_in[2];
    const float* w2 = (const float*)d_in[3];
    const float* b2 = (const float*)d_in[4];
    float* out = (float*)d_out;

    char* wsb = (char*)d_ws;
    _Float16* w1fh = (_Float16*)(wsb);
    _Float16* w1fl = (_Float16*)(wsb + 0x90000);
    _Float16* w2fh = (_Float16*)(wsb + 0x120000);
    _Float16* w2fl = (_Float16*)(wsb + 0x130000);
    uint64_t* MA   = (uint64_t*)(wsb + 0x140000);
    uint64_t* MB   = (uint64_t*)(wsb + 0x240000);

    const size_t S_OFF = 0x340000;
    const size_t S_BYTES = (size_t)BATCH * HI * HI * 4;
    const bool use_ws = ws_size >= S_OFF + S_BYTES;
    float* S = use_ws ? (float*)(wsb + S_OFF) : out;

    prep_wf<<<1232, 256, 0, stream>>>(w1, w2, w1fh, w1fl, w2fh, w2fl);
    head_kernel<<<dim3(8, 8, BATCH), 256, 0, stream>>>(
        x, w1fh, w1fl, w2fh, w2fl, b1, b2, S);

    dim3 g(NWORDS, 8, BATCH);
    nms_iter<<<g, 256, 0, stream>>>(S, nullptr, MA);   // init
    nms_iter<<<g, 256, 0, stream>>>(S, MA, MB);        // u1
    nms_iter<<<g, 256, 0, stream>>>(S, MB, MA);        // u2
    nms_iter<<<g, 256, 0, stream>>>(S, MA, MB);        // u3
    nms_iter<<<g, 256, 0, stream>>>(S, MB, MA);        // u4
    nms_iter<<<g, 256, 0, stream>>>(S, MA, MB);        // u5
    nms_iter<<<g, 256, 0, stream>>>(S, MB, MA);        // u6
    nms_iter<<<g, 256, 0, stream>>>(S, MA, MB);        // u7

    if (use_ws) {
        nms_last<<<g, 256, 0, stream>>>(S, MB, out);   // u8 + finalize
    } else {
        nms_iter<<<g, 256, 0, stream>>>(S, MB, MA);    // u8
        const int nf4 = BATCH * HI * HI / 4;
        finalize_bits<<<nf4 / 256, 256, 0, stream>>>(out, MA);
    }
}

// Round 11
// 495.077 us; speedup vs baseline: 12.2804x; 1.0538x over previous
//
#include <hip/hip_runtime.h>
#include <hip/hip_bf16.h>
#include <stdint.h>

#define BATCH 32
#define CIN 128
#define HH 64
#define WW 64
#define MID 256
#define NCLS 65
#define HI 512
#define NWORDS 8      // 512 cols / 64 bits
#define HBS2 264      // hb row stride (halfs)
#define SEMS 68       // sem row stride (floats)
#define RMS 68        // rm row stride (floats)

typedef _Float16 half8 __attribute__((ext_vector_type(8)));
typedef _Float16 half4v __attribute__((ext_vector_type(4)));
typedef _Float16 half2v __attribute__((ext_vector_type(2)));
typedef float f32x4 __attribute__((ext_vector_type(4)));

// ---------------------------------------------------------------------------
// Merged weight prep (full f16 hi/lo split — REQUIRED: NMS argmax stability
// needs exact-level logits; round-10 showed dropping the weight residue
// flips keep bits). Also zeroes the convergence flags.
// ---------------------------------------------------------------------------
__global__ __launch_bounds__(256) void prep_wf(
    const float* __restrict__ w1, const float* __restrict__ w2,
    _Float16* __restrict__ w1fh, _Float16* __restrict__ w1fl,
    _Float16* __restrict__ w2fh, _Float16* __restrict__ w2fl,
    int* __restrict__ flags)
{
    if (blockIdx.x == 0 && threadIdx.x < 16) flags[threadIdx.x] = 0;
    const int idx = blockIdx.x * 256 + threadIdx.x;   // < 315392
    if (idx < 294912) {
        const int j = idx & 7, lane = (idx >> 3) & 63, mt = (idx >> 9) & 15;
        const int s = (idx >> 13) & 3, kix = idx >> 15;
        const int m = mt * 16 + (lane & 15);
        const int c = s * 32 + (lane >> 4) * 8 + j;
        const int ky = kix / 3, kx = kix - ky * 3;
        const float v = w1[((m * CIN + c) * 3 + ky) * 3 + kx];
        const _Float16 hi = (_Float16)v;
        w1fh[idx] = hi;
        w1fl[idx] = (_Float16)(v - (float)hi);
    } else {
        const int i2 = idx - 294912;                  // < 20480
        const int j = i2 & 7, lane = (i2 >> 3) & 63;
        const int ks = (i2 >> 9) & 7, mt = i2 >> 12;
        const int o = mt * 16 + (lane & 15);
        const int k = ks * 32 + (lane >> 4) * 8 + j;
        const float v = (o < NCLS) ? w2[o * MID + k] : 0.f;
        const _Float16 hi = (_Float16)v;
        w2fh[i2] = hi;
        w2fl[i2] = (_Float16)(v - (float)hi);
    }
}

// ---------------------------------------------------------------------------
// MFMA head (verified ~250 us): conv3x3 via 9 shifted GEMMs (f16 3-product
// split), bias+relu -> 1x1 MFMA -> softmax -> threshold.
// __launch_bounds__(256,3): total regs <=170 (unified VGPR+AGPR) -> 3 blk/CU.
// ---------------------------------------------------------------------------
__global__ __launch_bounds__(256, 3) void head_kernel(
    const float* __restrict__ x,
    const _Float16* __restrict__ w1fh, const _Float16* __restrict__ w1fl,
    const _Float16* __restrict__ w2fh, const _Float16* __restrict__ w2fl,
    const float* __restrict__ b1, const float* __restrict__ b2,
    float* __restrict__ out)
{
    const int b  = blockIdx.z;
    const int y0 = blockIdx.y * 8, x0 = blockIdx.x * 8;
    const int tid = threadIdx.x;
    const int lane = tid & 63, w = tid >> 6;
    const int n = lane & 15, q = lane >> 4;

    __shared__ __align__(16) unsigned char SM[51200];
    char* const xhb = (char*)SM;                   // hi plane, 100*256 B
    _Float16* const hbh = (_Float16*)SM;           // [32][HBS2] (overlays xps)
    _Float16* const hbl = hbh + 32 * HBS2;
    float* const sem  = (float*)(SM + 33792);      // [32][SEMS]
    float* const rinv = sem + 32 * SEMS;           // [32]

    const float* xb = x + (size_t)b * CIN * HH * WW;
    for (int i = tid; i < 6400; i += 256) {
        const int c2 = i / 100, pos = i - c2 * 100;
        const int r = pos / 10, cc = pos - r * 10;
        const int gy = y0 - 1 + r, gx = x0 - 1 + cc;
        float v0 = 0.f, v1 = 0.f;
        if ((unsigned)gy < HH && (unsigned)gx < WW) {
            const float* p = xb + (c2 * 2 * HH + gy) * WW + gx;
            v0 = p[0]; v1 = p[HH * WW];
        }
        const _Float16 h0 = (_Float16)v0, h1 = (_Float16)v1;
        half2v hi = {h0, h1};
        half2v lo = {(_Float16)(v0 - (float)h0), (_Float16)(v1 - (float)h1)};
        const int slot = (c2 >> 2) ^ (pos & 15);
        char* p16 = xhb + pos * 256 + (slot << 4) + (c2 & 3) * 4;
        *(half2v*)p16 = hi;
        *(half2v*)(p16 + 25600) = lo;
    }
    __syncthreads();

    f32x4 acc[4][4];
#pragma unroll
    for (int i = 0; i < 4; ++i)
#pragma unroll
        for (int t = 0; t < 4; ++t) acc[i][t] = (f32x4){0.f, 0.f, 0.f, 0.f};

    int bposT[4];
#pragma unroll
    for (int t = 0; t < 4; ++t)
        bposT[t] = (t * 2 + (n >> 3)) * 10 + (n & 7);

    for (int kix = 0; kix < 9; ++kix) {
        const int ky = kix / 3;
        const int koff = ky * 10 + (kix - ky * 3);
#pragma unroll
        for (int s = 0; s < 4; ++s) {
            half8 Bh[4], Bl[4];
#pragma unroll
            for (int t = 0; t < 4; ++t) {
                const int pos = bposT[t] + koff;
                const int byteoff = pos * 256 +
                    ((((s << 2) + q) ^ (pos & 15)) << 4);
                Bh[t] = *(const half8*)(xhb + byteoff);
                Bl[t] = *(const half8*)(xhb + 25600 + byteoff);
            }
#pragma unroll
            for (int i = 0; i < 4; ++i) {
                const size_t o = (size_t)(kix * 4 + s) * 8192 +
                                 (w * 4 + i) * 512 + lane * 8;
                const half8 Ah = *(const half8*)(w1fh + o);
                const half8 Al = *(const half8*)(w1fl + o);
#pragma unroll
                for (int t = 0; t < 4; ++t) {
                    acc[i][t] = __builtin_amdgcn_mfma_f32_16x16x32_f16(
                        Ah, Bh[t], acc[i][t], 0, 0, 0);
                    acc[i][t] = __builtin_amdgcn_mfma_f32_16x16x32_f16(
                        Ah, Bl[t], acc[i][t], 0, 0, 0);
                    acc[i][t] = __builtin_amdgcn_mfma_f32_16x16x32_f16(
                        Al, Bh[t], acc[i][t], 0, 0, 0);
                }
            }
        }
    }
    __syncthreads();

    for (int hf = 0; hf < 2; ++hf) {
        if (hf) __syncthreads();
#pragma unroll
        for (int i = 0; i < 4; ++i)
#pragma unroll
            for (int tt = 0; tt < 2; ++tt) {
                const int t = hf * 2 + tt;
                const int p = tt * 16 + n;
                const int m0 = w * 64 + i * 16 + q * 4;
                const f32x4 a = acc[i][t];
                const float4 bv = *(const float4*)(b1 + m0);
                const float h0 = fmaxf(a[0] + bv.x, 0.f);
                const float h1 = fmaxf(a[1] + bv.y, 0.f);
                const float h2 = fmaxf(a[2] + bv.z, 0.f);
                const float h3 = fmaxf(a[3] + bv.w, 0.f);
                half4v hh = {(_Float16)h0, (_Float16)h1,
                             (_Float16)h2, (_Float16)h3};
                half4v hl = {(_Float16)(h0 - (float)hh[0]),
                             (_Float16)(h1 - (float)hh[1]),
                             (_Float16)(h2 - (float)hh[2]),
                             (_Float16)(h3 - (float)hh[3])};
                *(half4v*)(hbh + p * HBS2 + m0) = hh;
                *(half4v*)(hbl + p * HBS2 + m0) = hl;
            }
        __syncthreads();
        {
            const int nt = w & 1;
            const int mt0 = (w < 2) ? 0 : 3;
            const int nmt = (w < 2) ? 3 : 2;
            const int pb = nt * 16 + n;
            f32x4 a2[3];
#pragma unroll
            for (int j = 0; j < 3; ++j) a2[j] = (f32x4){0.f, 0.f, 0.f, 0.f};
#pragma unroll
            for (int ks = 0; ks < 8; ++ks) {
                const int ad = pb * HBS2 + ks * 32 + q * 8;
                const half8 B2h = *(const half8*)(hbh + ad);
                const half8 B2l = *(const half8*)(hbl + ad);
#pragma unroll
                for (int j = 0; j < 3; ++j)
                    if (j < nmt) {
                        const size_t o = (size_t)((mt0 + j) * 8 + ks) * 512 +
                                         lane * 8;
                        const half8 A2h = *(const half8*)(w2fh + o);
                        const half8 A2l = *(const half8*)(w2fl + o);
                        a2[j] = __builtin_amdgcn_mfma_f32_16x16x32_f16(
                            A2h, B2h, a2[j], 0, 0, 0);
                        a2[j] = __builtin_amdgcn_mfma_f32_16x16x32_f16(
                            A2h, B2l, a2[j], 0, 0, 0);
                        a2[j] = __builtin_amdgcn_mfma_f32_16x16x32_f16(
                            A2l, B2h, a2[j], 0, 0, 0);
                    }
            }
#pragma unroll
            for (int j = 0; j < 3; ++j)
                if (j < nmt) {
                    const int o0 = (mt0 + j) * 16 + q * 4;
#pragma unroll
                    for (int r2 = 0; r2 < 4; ++r2) {
                        const int o = o0 + r2;
                        if (o < NCLS)
                            sem[pb * SEMS + o] = a2[j][r2] + b2[o];
                    }
                }
        }
        __syncthreads();
        if (tid < 128) {
            const int p = tid >> 2, q4 = tid & 3;
            const int o0 = q4 * 17;
            const int o1 = (o0 + 17 < NCLS) ? o0 + 17 : NCLS;
            float mx = -1e30f;
            for (int o = o0; o < o1; ++o)
                mx = fmaxf(mx, sem[p * SEMS + o]);
            mx = fmaxf(mx, __shfl_xor(mx, 1));
            mx = fmaxf(mx, __shfl_xor(mx, 2));
            float ssum = 0.f;
            for (int o = o0; o < o1; ++o) {
                float e = __expf(sem[p * SEMS + o] - mx);
                sem[p * SEMS + o] = e;
                ssum += e;
            }
            ssum += __shfl_xor(ssum, 1);
            ssum += __shfl_xor(ssum, 2);
            if (q4 == 0) rinv[p] = 1.f / ssum;
        }
        __syncthreads();
        for (int t2 = tid; t2 < 2048; t2 += 256) {
            const int p = t2 >> 6, o = t2 & 63;
            float v = sem[p * SEMS + o] * rinv[p];
            if (!(v >= 0.015f)) v = 0.f;
            const int P = hf * 32 + p;
            const int py = P >> 3, px = P & 7;
            const int row = (y0 + py) * 8 + (o >> 3);
            const int col = (x0 + px) * 8 + (o & 7);
            out[((size_t)b * HI + row) * HI + col] = v;
        }
    }
}

// ---------------------------------------------------------------------------
// hmax phase helper (verified round 9): own-float4 loads + __shfl halo.
// ---------------------------------------------------------------------------
__device__ __forceinline__ void nms_hmax_phase(
    const float* __restrict__ Sb, const uint64_t* __restrict__ sup,
    float* __restrict__ rm, int ty, int tx, int tid, int rbase)
{
    const int lane = tid & 63;
    for (int k = tid; k < 640; k += 256) {
        const int rr = k >> 4, g = k & 15;
        const int r = rbase + rr;
        const int gy = ty - 4 + r;
        const int x4 = g * 4;
        const uint64_t* sr = sup + r * 3;
        float own[4] = {0.f, 0.f, 0.f, 0.f};
        float halo[4] = {0.f, 0.f, 0.f, 0.f};
        if ((unsigned)gy < HI) {
            const float* row = Sb + (size_t)gy * HI;
            const float4 o4 = *(const float4*)(row + tx + x4);
            own[0] = o4.x; own[1] = o4.y; own[2] = o4.z; own[3] = o4.w;
            const uint64_t w1 = sr[1];
#pragma unroll
            for (int cc = 0; cc < 4; ++cc)
                if ((w1 >> (x4 + cc)) & 1ull) own[cc] = 0.f;
            if (g == 0 && tx >= 4) {
                const float4 h4 = *(const float4*)(row + tx - 4);
                halo[0] = h4.x; halo[1] = h4.y; halo[2] = h4.z; halo[3] = h4.w;
                const uint64_t w0 = sr[0];
#pragma unroll
                for (int cc = 0; cc < 4; ++cc)
                    if ((w0 >> (60 + cc)) & 1ull) halo[cc] = 0.f;
            } else if (g == 15 && tx + 64 < HI) {
                const float4 h4 = *(const float4*)(row + tx + 64);
                halo[0] = h4.x; halo[1] = h4.y; halo[2] = h4.z; halo[3] = h4.w;
                const uint64_t w2 = sr[2];
#pragma unroll
                for (int cc = 0; cc < 4; ++cc)
                    if ((w2 >> cc) & 1ull) halo[cc] = 0.f;
            }
        }
        float v[12];
#pragma unroll
        for (int cc = 0; cc < 4; ++cc) {
            v[4 + cc] = own[cc];
            v[cc]     = __shfl(own[cc], lane - 1);
            v[8 + cc] = __shfl(own[cc], lane + 1);
        }
        if (g == 0) {
#pragma unroll
            for (int cc = 0; cc < 4; ++cc) v[cc] = halo[cc];
        } else if (g == 15) {
#pragma unroll
            for (int cc = 0; cc < 4; ++cc) v[8 + cc] = halo[cc];
        }
        const float m4567 = fmaxf(fmaxf(v[4],v[5]), fmaxf(v[6],v[7]));
        const float m23 = fmaxf(v[2],v[3]), m89 = fmaxf(v[8],v[9]);
        const float o0 = fmaxf(fmaxf(fmaxf(v[0],v[1]), m23),
                               fmaxf(m4567, v[8]));
        const float o1 = fmaxf(fmaxf(v[1], m23), fmaxf(m4567, m89));
        const float o2 = fmaxf(fmaxf(m23, m4567), fmaxf(m89, v[10]));
        const float o3 = fmaxf(fmaxf(v[3], m4567),
                               fmaxf(fmaxf(m89, v[10]), v[11]));
        *(float4*)(rm + rr * RMS + x4) = make_float4(o0,o1,o2,o3);
    }
}

// ---------------------------------------------------------------------------
// Lean NMS iteration + convergence early-out. If flags[chk]==0 the previous
// iteration was the identity -> this one is too (determinism): just copy
// Min->Mout. Otherwise compute fully; lane 0 records any word change to
// flags[set] (cross-kernel visibility via launch-boundary flush, same
// mechanism as the mask ping-pong itself).
// ---------------------------------------------------------------------------
__global__ __launch_bounds__(256, 8) void nms_iter(
    const float* __restrict__ S, const uint64_t* __restrict__ Min,
    uint64_t* __restrict__ Mout, int* __restrict__ flags, int chk, int set)
{
    const int b = blockIdx.z;
    const int bx = blockIdx.x;
    const int ty = blockIdx.y * 64, tx = bx * 64;
    const int tid = threadIdx.x;

    if (chk >= 0 && flags[chk] == 0) {
        for (int y = tid; y < 64; y += 256)
            Mout[((size_t)b * HI + ty + y) * NWORDS + bx] =
                Min[((size_t)b * HI + ty + y) * NWORDS + bx];
        return;
    }

    __shared__ uint64_t smw[80 * 3];
    __shared__ uint64_t hd[80 * 3];
    __shared__ uint64_t sup[72 * 3];
    __shared__ __align__(16) float rm[40 * RMS];

    const float* Sb = S + (size_t)b * HI * HI;
    int chg = 0;

    if (Min) {
        if (tid < 240) {
            const int i = tid / 3, j = tid % 3;
            const int yy = ty - 8 + i;
            const int wj = bx - 1 + j;
            uint64_t v = 0;
            if ((unsigned)yy < HI && (unsigned)wj < NWORDS)
                v = Min[((size_t)b * HI + yy) * NWORDS + wj];
            smw[tid] = v;
        }
        __syncthreads();
        if (tid < 240) {
            const int j = tid % 3;
            const uint64_t c = smw[tid];
            const uint64_t l = j > 0 ? smw[tid - 1] : 0ull;
            const uint64_t r = j < 2 ? smw[tid + 1] : 0ull;
            uint64_t d = c;
#pragma unroll
            for (int s = 1; s <= 4; ++s)
                d |= (c >> s) | (r << (64 - s)) | (c << s) | (l >> (64 - s));
            hd[tid] = d;
        }
        __syncthreads();
        if (tid < 216) {
            uint64_t v = 0;
#pragma unroll
            for (int k = 0; k < 9; ++k) v |= hd[tid + 3 * k];
            sup[tid] = v;
        }
        __syncthreads();
    } else {
        if (tid < 240) smw[tid] = 0;
        if (tid < 216) sup[tid] = 0;
        __syncthreads();
    }

    for (int half = 0; half < 2; ++half) {
        const int rbase = half * 32;
        nms_hmax_phase(Sb, sup, rm, ty, tx, tid, rbase);
        __syncthreads();
        {
            const int wv = tid >> 6, lane = tid & 63;
            const int rb = wv * 8;
            const int ybase = rbase + rb;
            float ring[9];
#pragma unroll
            for (int k = 0; k < 8; ++k) ring[k] = rm[(rb + k) * RMS + lane];
#pragma unroll
            for (int qq = 0; qq < 8; ++qq) {
                const int y = ybase + qq;
                ring[(qq + 8) % 9] = rm[(rb + qq + 8) * RMS + lane];
                float mv = ring[0];
#pragma unroll
                for (int k = 1; k < 9; ++k) mv = fmaxf(mv, ring[k]);
                float c = Sb[(size_t)(ty + y) * HI + tx + lane];
                if ((sup[(y + 4) * 3 + 1] >> lane) & 1ull) c = 0.f;
                const uint64_t oldw = smw[(y + 8) * 3 + 1];
                const bool keep = ((oldw >> lane) & 1ull) ||
                                  (c > 0.f && c == mv);
                const uint64_t word = __ballot(keep);
                if (lane == 0) {
                    Mout[((size_t)b * HI + ty + y) * NWORDS + bx] = word;
                    if (word != oldw) chg = 1;
                }
            }
        }
        __syncthreads();
    }
    if (set >= 0 && (tid & 63) == 0 && chg) flags[set] = 1;
}

// ---------------------------------------------------------------------------
// Last NMS update (u8) fused with finalize. Fast path when flags[7]==0:
// mask is final, apply (bit && border) ? S : 0 directly.
// ---------------------------------------------------------------------------
__global__ __launch_bounds__(256, 8) void nms_last(
    const float* __restrict__ S, const uint64_t* __restrict__ Min,
    float* __restrict__ out, const int* __restrict__ flags)
{
    const int b = blockIdx.z;
    const int bx = blockIdx.x;
    const int ty = blockIdx.y * 64, tx = bx * 64;
    const int tid = threadIdx.x;

    const float* Sb = S + (size_t)b * HI * HI;

    if (flags[7] == 0) {
        for (int k = tid; k < 1024; k += 256) {
            const int r = k >> 4, c4 = k & 15;
            const int gy = ty + r;
            const int gx0 = tx + c4 * 4;
            const uint64_t w = Min[((size_t)b * HI + gy) * NWORDS + bx];
            float4 v = *(const float4*)(Sb + (size_t)gy * HI + gx0);
            float* pv = (float*)&v;
            const bool rowok = (gy >= 4) && (gy < HI - 4);
#pragma unroll
            for (int cc = 0; cc < 4; ++cc) {
                const int xx = gx0 + cc;
                const bool keep = rowok && (xx >= 4) && (xx < HI - 4) &&
                                  ((w >> ((c4 * 4 + cc) & 63)) & 1ull);
                if (!keep) pv[cc] = 0.f;
            }
            *(float4*)(out + ((size_t)b * HI + gy) * HI + gx0) = v;
        }
        return;
    }

    __shared__ uint64_t smw[80 * 3];
    __shared__ uint64_t hd[80 * 3];
    __shared__ uint64_t sup[72 * 3];
    __shared__ __align__(16) float rm[40 * RMS];

    if (tid < 240) {
        const int i = tid / 3, j = tid % 3;
        const int yy = ty - 8 + i;
        const int wj = bx - 1 + j;
        uint64_t v = 0;
        if ((unsigned)yy < HI && (unsigned)wj < NWORDS)
            v = Min[((size_t)b * HI + yy) * NWORDS + wj];
        smw[tid] = v;
    }
    __syncthreads();
    if (tid < 240) {
        const int j = tid % 3;
        const uint64_t c = smw[tid];
        const uint64_t l = j > 0 ? smw[tid - 1] : 0ull;
        const uint64_t r = j < 2 ? smw[tid + 1] : 0ull;
        uint64_t d = c;
#pragma unroll
        for (int s = 1; s <= 4; ++s)
            d |= (c >> s) | (r << (64 - s)) | (c << s) | (l >> (64 - s));
        hd[tid] = d;
    }
    __syncthreads();
    if (tid < 216) {
        uint64_t v = 0;
#pragma unroll
        for (int k = 0; k < 9; ++k) v |= hd[tid + 3 * k];
        sup[tid] = v;
    }
    __syncthreads();

    for (int half = 0; half < 2; ++half) {
        const int rbase = half * 32;
        nms_hmax_phase(Sb, sup, rm, ty, tx, tid, rbase);
        __syncthreads();
        {
            const int wv = tid >> 6, lane = tid & 63;
            const int rb = wv * 8;
            const int ybase = rbase + rb;
            float ring[9];
#pragma unroll
            for (int k = 0; k < 8; ++k) ring[k] = rm[(rb + k) * RMS + lane];
#pragma unroll
            for (int qq = 0; qq < 8; ++qq) {
                const int y = ybase + qq;
                ring[(qq + 8) % 9] = rm[(rb + qq + 8) * RMS + lane];
                float mv = ring[0];
#pragma unroll
                for (int k = 1; k < 9; ++k) mv = fmaxf(mv, ring[k]);
                const int gy = ty + y, gx = tx + lane;
                const float corig = Sb[(size_t)gy * HI + gx];
                float c = corig;
                if ((sup[(y + 4) * 3 + 1] >> lane) & 1ull) c = 0.f;
                const uint64_t oldw = smw[(y + 8) * 3 + 1];
                const bool keep = ((oldw >> lane) & 1ull) ||
                                  (c > 0.f && c == mv);
                const bool border = (gy >= 4) && (gy < HI - 4) &&
                                    (gx >= 4) && (gx < HI - 4);
                out[((size_t)b * HI + gy) * HI + gx] =
                    (keep && border) ? corig : 0.f;
            }
        }
        __syncthreads();
    }
}

// ---------------------------------------------------------------------------
// Fallback finalize (only used when ws too small for S).
// ---------------------------------------------------------------------------
__global__ __launch_bounds__(256) void finalize_bits(
    float* __restrict__ S, const uint64_t* __restrict__ Mw)
{
    const int i4 = blockIdx.x * 256 + threadIdx.x;
    const size_t base = (size_t)i4 * 4;
    const int x = (int)(base & 511);
    const int y = (int)((base >> 9) & 511);
    const int bb = (int)(base >> 18);
    const uint64_t w = Mw[((size_t)bb * HI + y) * NWORDS + (x >> 6)];
    float4 v = ((const float4*)S)[i4];
    float* pv = (float*)&v;
    const bool rowok = (y >= 4) && (y < HI - 4);
#pragma unroll
    for (int cc = 0; cc < 4; ++cc) {
        const int xx = x + cc;
        const bool keep = rowok && (xx >= 4) && (xx < HI - 4) &&
                          ((w >> (xx & 63)) & 1ull);
        if (!keep) pv[cc] = 0.f;
    }
    ((float4*)S)[i4] = v;
}

extern "C" void kernel_launch(void* const* d_in, const int* in_sizes, int n_in,
                              void* d_out, int out_size, void* d_ws, size_t ws_size,
                              hipStream_t stream) {
    const float* x  = (const float*)d_in[0];
    const float* w1 = (const float*)d_in[1];
    const float* b1 = (const float*)d_in[2];
    const float* w2 = (const float*)d_in[3];
    const float* b2 = (const float*)d_in[4];
    float* out = (float*)d_out;

    char* wsb = (char*)d_ws;
    _Float16* w1fh = (_Float16*)(wsb);
    _Float16* w1fl = (_Float16*)(wsb + 0x90000);
    _Float16* w2fh = (_Float16*)(wsb + 0x120000);
    _Float16* w2fl = (_Float16*)(wsb + 0x130000);
    int* flags     = (int*)(wsb + 0x13B000);
    uint64_t* MA   = (uint64_t*)(wsb + 0x140000);
    uint64_t* MB   = (uint64_t*)(wsb + 0x240000);

    const size_t S_OFF = 0x340000;
    const size_t S_BYTES = (size_t)BATCH * HI * HI * 4;
    const bool use_ws = ws_size >= S_OFF + S_BYTES;
    float* S = use_ws ? (float*)(wsb + S_OFF) : out;

    prep_wf<<<1232, 256, 0, stream>>>(w1, w2, w1fh, w1fl, w2fh, w2fl, flags);
    head_kernel<<<dim3(8, 8, BATCH), 256, 0, stream>>>(
        x, w1fh, w1fl, w2fh, w2fl, b1, b2, S);

    dim3 g(NWORDS, 8, BATCH);
    // init + u1 never fast-path; u1 records flags[1]; uK checks flags[K-1].
    nms_iter<<<g, 256, 0, stream>>>(S, nullptr, MA, flags, -1, -1); // init
    nms_iter<<<g, 256, 0, stream>>>(S, MA, MB, flags, -1, 1);       // u1
    nms_iter<<<g, 256, 0, stream>>>(S, MB, MA, flags, 1, 2);        // u2
    nms_iter<<<g, 256, 0, stream>>>(S, MA, MB, flags, 2, 3);        // u3
    nms_iter<<<g, 256, 0, stream>>>(S, MB, MA, flags, 3, 4);        // u4
    nms_iter<<<g, 256, 0, stream>>>(S, MA, MB, flags, 4, 5);        // u5
    nms_iter<<<g, 256, 0, stream>>>(S, MB, MA, flags, 5, 6);        // u6
    nms_iter<<<g, 256, 0, stream>>>(S, MA, MB, flags, 6, 7);        // u7

    if (use_ws) {
        nms_last<<<g, 256, 0, stream>>>(S, MB, out, flags);         // u8
    } else {
        nms_iter<<<g, 256, 0, stream>>>(S, MB, MA, flags, 7, -1);   // u8
        const int nf4 = BATCH * HI * HI / 4;
        finalize_bits<<<nf4 / 256, 256, 0, stream>>>(out, MA);
    }
}